// Round 1
// baseline (10198.241 us; speedup 1.0000x reference)
//
#include <hip/hip_runtime.h>
#include <hip/hip_bf16.h>
#include <math.h>

#define C_IN   32
#define D0     64
#define H0     96
#define W0     192
#define DD     193
#define HH     288
#define WW     576
#define NPIX   (HH*WW)            // 165888
#define NVOL   ((size_t)DD*NPIX)  // 32,016,384
#define NCOST  (D0*H0*W0)         // 1,179,648

// ---------------- conv3d: x(32,64,96,192) * w(32,3,3,3) -> cost(64,96,192), pad=1
__global__ void conv3d_kernel(const float* __restrict__ x,
                              const float* __restrict__ w,
                              float* __restrict__ cost) {
    int wx = blockIdx.x * 64 + threadIdx.x;   // 0..191
    int y  = blockIdx.y * 4  + threadIdx.y;   // 0..95
    int z  = blockIdx.z;                      // 0..63
    float acc = 0.f;
    for (int ci = 0; ci < C_IN; ++ci) {
        const float* xc = x + (size_t)ci * D0 * H0 * W0;
        const float* wc = w + ci * 27;
        #pragma unroll
        for (int kd = 0; kd < 3; ++kd) {
            int zz = z + kd - 1;
            if (zz < 0 || zz >= D0) continue;
            #pragma unroll
            for (int kh = 0; kh < 3; ++kh) {
                int yy = y + kh - 1;
                if (yy < 0 || yy >= H0) continue;
                #pragma unroll
                for (int kw = 0; kw < 3; ++kw) {
                    int xx = wx + kw - 1;
                    if (xx < 0 || xx >= W0) continue;
                    acc += xc[((size_t)zz * H0 + yy) * W0 + xx] * wc[(kd * 3 + kh) * 3 + kw];
                }
            }
        }
    }
    cost[((size_t)z * H0 + y) * W0 + wx] = acc;
}

// ---------------- per-pixel 1/L1-norm over 75 guidance channels
__global__ void invnorm_kernel(const float* __restrict__ lg, float* __restrict__ inv) {
    int pix = blockIdx.x * 256 + threadIdx.x;
    if (pix >= NPIX) return;
    float s = 0.f;
    for (int c = 0; c < 75; ++c) s += fabsf(lg[(size_t)c * NPIX + pix]);
    inv[pix] = 1.0f / fmaxf(s, 1e-12f);
}

// ---------------- trilinear resize cost(64,96,192) -> out(193,288,576)
__global__ void resize_kernel(const float* __restrict__ cost, float* __restrict__ out) {
    size_t idx = (size_t)blockIdx.x * 256 + threadIdx.x;
    if (idx >= NVOL) return;
    int w = (int)(idx % WW);
    int t = (int)(idx / WW);
    int h = t % HH;
    int d = t / HH;

    float sd = fminf(fmaxf((d + 0.5f) * (64.0f / 193.0f) - 0.5f, 0.0f), 63.0f);
    int d0 = (int)floorf(sd); int d1 = min(d0 + 1, 63); float fd = sd - (float)d0;
    float sh = fminf(fmaxf((h + 0.5f) * (96.0f / 288.0f) - 0.5f, 0.0f), 95.0f);
    int h0 = (int)floorf(sh); int h1 = min(h0 + 1, 95); float fh = sh - (float)h0;
    float sw = fminf(fmaxf((w + 0.5f) * (192.0f / 576.0f) - 0.5f, 0.0f), 191.0f);
    int w0 = (int)floorf(sw); int w1 = min(w0 + 1, 191); float fw = sw - (float)w0;

    #define CV(dz, hy, wx) cost[((size_t)(dz) * H0 + (hy)) * W0 + (wx)]
    float v000 = CV(d0, h0, w0), v001 = CV(d0, h0, w1);
    float v010 = CV(d0, h1, w0), v011 = CV(d0, h1, w1);
    float v100 = CV(d1, h0, w0), v101 = CV(d1, h0, w1);
    float v110 = CV(d1, h1, w0), v111 = CV(d1, h1, w1);
    #undef CV
    float a = v000 * (1.f - fw) + v001 * fw;
    float b = v010 * (1.f - fw) + v011 * fw;
    float c = v100 * (1.f - fw) + v101 * fw;
    float e = v110 * (1.f - fw) + v111 * fw;
    float lo = a * (1.f - fh) + b * fh;
    float hi = c * (1.f - fh) + e * fh;
    out[idx] = lo * (1.f - fd) + hi * fd;
}

// ---------------- one LGA pass: out[d,h,w] = sum_{dd,i,j} gN[dd,i,j;h,w] * in[d+dd-1, h+i-2, w+j-2]
// gN = g * inv (L1-normalized). Optional per-source-pixel inscale folds the softmax denominator.
// Decomposition: per slice e compute 3 spatial 5x5 convs (c0,c1,c2), scatter to out[e+1],out[e],out[e-1].
__global__ void lga_kernel(const float* __restrict__ in, float* __restrict__ out,
                           const float* __restrict__ g, const float* __restrict__ inv,
                           const float* __restrict__ inscale) {
    int w = blockIdx.x * 64 + threadIdx.x;  // 0..575
    int h = blockIdx.y;                      // 0..287
    int pix = h * WW + w;
    float s = inv[pix];

    float g0[25], g1[25], g2[25];
    #pragma unroll
    for (int c = 0; c < 25; ++c) g0[c] = g[(size_t)c * NPIX + pix] * s;
    #pragma unroll
    for (int c = 0; c < 25; ++c) g1[c] = g[(size_t)(25 + c) * NPIX + pix] * s;
    #pragma unroll
    for (int c = 0; c < 25; ++c) g2[c] = g[(size_t)(50 + c) * NPIX + pix] * s;

    float isc[25];
    #pragma unroll
    for (int i = 0; i < 5; ++i) {
        #pragma unroll
        for (int j = 0; j < 5; ++j) {
            int hh = h + i - 2, ww = w + j - 2;
            bool v = (unsigned)hh < (unsigned)HH && (unsigned)ww < (unsigned)WW;
            isc[i * 5 + j] = (inscale != nullptr && v) ? inscale[hh * WW + ww] : 1.0f;
        }
    }

    float accA = 0.f, accB = 0.f;
    for (int e = 0; e < DD; ++e) {
        const float* sl = in + (size_t)e * NPIX;
        float c0 = 0.f, c1 = 0.f, c2 = 0.f;
        #pragma unroll
        for (int i = 0; i < 5; ++i) {
            int hh = h + i - 2;
            bool vy = (unsigned)hh < (unsigned)HH;
            #pragma unroll
            for (int j = 0; j < 5; ++j) {
                int ww = w + j - 2;
                float v = (vy && (unsigned)ww < (unsigned)WW)
                            ? sl[hh * WW + ww] * isc[i * 5 + j] : 0.0f;
                c0 += g0[i * 5 + j] * v;
                c1 += g1[i * 5 + j] * v;
                c2 += g2[i * 5 + j] * v;
            }
        }
        float r = accA + c2;
        if (e >= 1) out[(size_t)(e - 1) * NPIX + pix] = r;
        accA = accB + c1;
        accB = c0;
    }
    out[(size_t)(DD - 1) * NPIX + pix] = accA;  // slice DD is zero-pad: no c2 term
}

// ---------------- softmax over d (axis 0 of (193,288,576)): write unnormalized exp, store recip-sum
__global__ void softmax_kernel(const float* __restrict__ in, float* __restrict__ out,
                               float* __restrict__ rdenom) {
    int pix = blockIdx.x * 256 + threadIdx.x;
    if (pix >= NPIX) return;
    float m = -3.4e38f;
    for (int d = 0; d < DD; ++d) m = fmaxf(m, -in[(size_t)d * NPIX + pix]);
    float s = 0.f;
    for (int d = 0; d < DD; ++d) {
        float e = __expf(-in[(size_t)d * NPIX + pix] - m);
        s += e;
        out[(size_t)d * NPIX + pix] = e;
    }
    rdenom[pix] = 1.0f / s;  // s >= 1 always (max term contributes exp(0)=1)
}

// ---------------- fused L1-normalize + disparity expectation
__global__ void final_kernel(const float* __restrict__ p, float* __restrict__ out) {
    int pix = blockIdx.x * 256 + threadIdx.x;
    if (pix >= NPIX) return;
    float A = 0.f, S = 0.f;
    for (int d = 0; d < DD; ++d) {
        float v = p[(size_t)d * NPIX + pix];
        A += v * (float)d;
        S += fabsf(v);
    }
    out[pix] = A / fmaxf(S, 1e-12f);
}

extern "C" void kernel_launch(void* const* d_in, const int* in_sizes, int n_in,
                              void* d_out, int out_size, void* d_ws, size_t ws_size,
                              hipStream_t stream) {
    const float* x    = (const float*)d_in[0];
    const float* lg1  = (const float*)d_in[1];
    const float* lg2  = (const float*)d_in[2];
    const float* cw   = (const float*)d_in[3];
    float* out = (float*)d_out;

    float* ws   = (float*)d_ws;
    float* buf0 = ws;
    float* buf1 = buf0 + NVOL;
    float* cost = buf1 + NVOL;
    float* inv1 = cost + NCOST;
    float* inv2 = inv1 + NPIX;
    float* rden = inv2 + NPIX;

    // 1. conv3d
    conv3d_kernel<<<dim3(W0 / 64, H0 / 4, D0), dim3(64, 4), 0, stream>>>(x, cw, cost);
    // 2. guidance inverse L1 norms
    invnorm_kernel<<<(NPIX + 255) / 256, 256, 0, stream>>>(lg1, inv1);
    invnorm_kernel<<<(NPIX + 255) / 256, 256, 0, stream>>>(lg2, inv2);
    // 3. trilinear upsample
    resize_kernel<<<(int)((NVOL + 255) / 256), 256, 0, stream>>>(cost, buf0);
    // 4. LGA x2 with lg1
    lga_kernel<<<dim3(WW / 64, HH), 64, 0, stream>>>(buf0, buf1, lg1, inv1, nullptr);
    lga_kernel<<<dim3(WW / 64, HH), 64, 0, stream>>>(buf1, buf0, lg1, inv1, nullptr);
    // 5. softmax over d (unnormalized; denominator folded into next LGA)
    softmax_kernel<<<(NPIX + 255) / 256, 256, 0, stream>>>(buf0, buf1, rden);
    // 6. LGA x2 with lg2 (first applies softmax recip at source pixels)
    lga_kernel<<<dim3(WW / 64, HH), 64, 0, stream>>>(buf1, buf0, lg2, inv2, rden);
    lga_kernel<<<dim3(WW / 64, HH), 64, 0, stream>>>(buf0, buf1, lg2, inv2, nullptr);
    // 7. normalize + expectation
    final_kernel<<<(NPIX + 255) / 256, 256, 0, stream>>>(buf1, out);
}

// Round 3
// 1744.124 us; speedup vs baseline: 5.8472x; 5.8472x over previous
//
#include <hip/hip_runtime.h>
#include <hip/hip_bf16.h>
#include <math.h>

#define C_IN   32
#define D0     64
#define H0     96
#define W0     192
#define DD     193
#define HH     288
#define WW     576
#define NPIX   (HH*WW)            // 165888
#define NPIX4  (NPIX/4)           // 41472
#define NVOL   ((size_t)DD*NPIX)  // 32,016,384
#define NCOST  (D0*H0*W0)         // 1,179,648

// ---------------- conv3d: x(32,64,96,192) * w(32,3,3,3) -> cost(64,96,192), pad=1
__global__ void conv3d_kernel(const float* __restrict__ x,
                              const float* __restrict__ w,
                              float* __restrict__ cost) {
    int wx = blockIdx.x * 64 + threadIdx.x;   // 0..191
    int y  = blockIdx.y * 4  + threadIdx.y;   // 0..95
    int z  = blockIdx.z;                      // 0..63
    float acc = 0.f;
    for (int ci = 0; ci < C_IN; ++ci) {
        const float* xc = x + (size_t)ci * D0 * H0 * W0;
        const float* wc = w + ci * 27;
        #pragma unroll
        for (int kd = 0; kd < 3; ++kd) {
            int zz = z + kd - 1;
            if (zz < 0 || zz >= D0) continue;
            #pragma unroll
            for (int kh = 0; kh < 3; ++kh) {
                int yy = y + kh - 1;
                if (yy < 0 || yy >= H0) continue;
                #pragma unroll
                for (int kw = 0; kw < 3; ++kw) {
                    int xx = wx + kw - 1;
                    if (xx < 0 || xx >= W0) continue;
                    acc += xc[((size_t)zz * H0 + yy) * W0 + xx] * wc[(kd * 3 + kh) * 3 + kw];
                }
            }
        }
    }
    cost[((size_t)z * H0 + y) * W0 + wx] = acc;
}

// ---------------- per-pixel 1/L1-norm over 75 guidance channels (float4)
__global__ void invnorm_kernel(const float4* __restrict__ lg, float4* __restrict__ inv) {
    int p = blockIdx.x * 256 + threadIdx.x;
    if (p >= NPIX4) return;
    float4 s = {0.f, 0.f, 0.f, 0.f};
    for (int c = 0; c < 75; ++c) {
        float4 v = lg[(size_t)c * NPIX4 + p];
        s.x += fabsf(v.x); s.y += fabsf(v.y); s.z += fabsf(v.z); s.w += fabsf(v.w);
    }
    float4 r;
    r.x = 1.0f / fmaxf(s.x, 1e-12f);
    r.y = 1.0f / fmaxf(s.y, 1e-12f);
    r.z = 1.0f / fmaxf(s.z, 1e-12f);
    r.w = 1.0f / fmaxf(s.w, 1e-12f);
    inv[p] = r;
}

// ---------------- trilinear resize cost(64,96,192) -> out(193,288,576)
__global__ void resize_kernel(const float* __restrict__ cost, float* __restrict__ out) {
    size_t idx = (size_t)blockIdx.x * 256 + threadIdx.x;
    if (idx >= NVOL) return;
    int w = (int)(idx % WW);
    int t = (int)(idx / WW);
    int h = t % HH;
    int d = t / HH;

    float sd = fminf(fmaxf((d + 0.5f) * (64.0f / 193.0f) - 0.5f, 0.0f), 63.0f);
    int d0 = (int)floorf(sd); int d1 = min(d0 + 1, 63); float fd = sd - (float)d0;
    float sh = fminf(fmaxf((h + 0.5f) * (96.0f / 288.0f) - 0.5f, 0.0f), 95.0f);
    int h0 = (int)floorf(sh); int h1 = min(h0 + 1, 95); float fh = sh - (float)h0;
    float sw = fminf(fmaxf((w + 0.5f) * (192.0f / 576.0f) - 0.5f, 0.0f), 191.0f);
    int w0 = (int)floorf(sw); int w1 = min(w0 + 1, 191); float fw = sw - (float)w0;

    #define CV(dz, hy, wx) cost[((size_t)(dz) * H0 + (hy)) * W0 + (wx)]
    float v000 = CV(d0, h0, w0), v001 = CV(d0, h0, w1);
    float v010 = CV(d0, h1, w0), v011 = CV(d0, h1, w1);
    float v100 = CV(d1, h0, w0), v101 = CV(d1, h0, w1);
    float v110 = CV(d1, h1, w0), v111 = CV(d1, h1, w1);
    #undef CV
    float a = v000 * (1.f - fw) + v001 * fw;
    float b = v010 * (1.f - fw) + v011 * fw;
    float c = v100 * (1.f - fw) + v101 * fw;
    float e = v110 * (1.f - fw) + v111 * fw;
    float lo = a * (1.f - fh) + b * fh;
    float hi = c * (1.f - fh) + e * fh;
    out[idx] = lo * (1.f - fd) + hi * fd;
}

// ---------------- LDS-tiled LGA pass
// out[d,h,w] = sum_{dd,i,j} gN[dd,i,j;h,w] * in'[d+dd-1, h+i-2, w+j-2]
// in' = in * inscale (softmax denom folded at staging), gN = g*inv.
// Block: 512 threads = 64x8 pixel tile; per slice stage 68x12 halo in LDS
// (double-buffered, prefetch e+1 during compute of e). Depth handled with
// rolling accumulators (c2 -> out[e-1], c1 -> out[e], c0 -> out[e+1]).
#define TW 64
#define TH 8
#define HWT 68
#define HHT 12
#define NCELL (HWT*HHT)   // 816
#define NTHR 512

__global__ __launch_bounds__(NTHR)
void lga_tiled_kernel(const float* __restrict__ in, float* __restrict__ out,
                      const float* __restrict__ g, const float* __restrict__ inv,
                      const float* __restrict__ inscale) {
    __shared__ float sbuf[2][NCELL];
    const int tid = threadIdx.x;
    const int tx = tid & 63, ty = tid >> 6;
    const int wb = blockIdx.x * TW, hb = blockIdx.y * TH;
    const int pix = (hb + ty) * WW + (wb + tx);

    // --- per-thread staging cells (tile is 816 cells; each thread owns <=2)
    const int c0 = tid, c1 = tid + NTHR;
    const bool has1 = (c1 < NCELL);
    int r0 = c0 / HWT, q0 = c0 - r0 * HWT;
    int hh0 = hb - 2 + r0, ww0 = wb - 2 + q0;
    const bool v0 = (unsigned)hh0 < (unsigned)HH && (unsigned)ww0 < (unsigned)WW;
    const size_t off0 = v0 ? (size_t)hh0 * WW + ww0 : 0;
    const float is0 = (inscale != nullptr && v0) ? inscale[off0] : 1.0f;
    int r1 = c1 / HWT, q1 = c1 - r1 * HWT;
    int hh1 = hb - 2 + r1, ww1 = wb - 2 + q1;
    const bool v1 = has1 && (unsigned)hh1 < (unsigned)HH && (unsigned)ww1 < (unsigned)WW;
    const size_t off1 = v1 ? (size_t)hh1 * WW + ww1 : 0;
    const float is1 = (inscale != nullptr && v1) ? inscale[off1] : 1.0f;

    // --- normalized guidance weights in registers (75 VGPRs)
    const float s = inv[pix];
    float g0[25], g1[25], g2[25];
    #pragma unroll
    for (int c = 0; c < 25; ++c) g0[c] = g[(size_t)c * NPIX + pix] * s;
    #pragma unroll
    for (int c = 0; c < 25; ++c) g1[c] = g[(size_t)(25 + c) * NPIX + pix] * s;
    #pragma unroll
    for (int c = 0; c < 25; ++c) g2[c] = g[(size_t)(50 + c) * NPIX + pix] * s;

    // --- stage slice 0
    {
        sbuf[0][c0] = v0 ? in[off0] * is0 : 0.0f;
        if (has1) sbuf[0][c1] = v1 ? in[off1] * is1 : 0.0f;
    }

    float accA = 0.f, accB = 0.f;
    for (int e = 0; e < DD; ++e) {
        __syncthreads();  // staging(e) complete; reads of buf[(e+1)&1] from e-1 complete
        if (e + 1 < DD) {
            const float* nsl = in + (size_t)(e + 1) * NPIX;
            float a = v0 ? nsl[off0] * is0 : 0.0f;
            float b = v1 ? nsl[off1] * is1 : 0.0f;
            float* nb = sbuf[(e + 1) & 1];
            nb[c0] = a;
            if (has1) nb[c1] = b;
        }
        const float* cur = sbuf[e & 1];
        float cc0 = 0.f, cc1 = 0.f, cc2 = 0.f;
        #pragma unroll
        for (int i = 0; i < 5; ++i) {
            const float* row = cur + (ty + i) * HWT + tx;
            #pragma unroll
            for (int j = 0; j < 5; ++j) {
                float v = row[j];
                cc0 += g0[i * 5 + j] * v;
                cc1 += g1[i * 5 + j] * v;
                cc2 += g2[i * 5 + j] * v;
            }
        }
        float rr = accA + cc2;
        if (e >= 1) out[(size_t)(e - 1) * NPIX + pix] = rr;
        accA = accB + cc1;
        accB = cc0;
    }
    out[(size_t)(DD - 1) * NPIX + pix] = accA;  // slice DD is zero-pad: no c2 term
}

// ---------------- softmax over d: write unnormalized exp + recip-sum (float4)
__global__ void softmax_kernel(const float4* __restrict__ in, float4* __restrict__ out,
                               float4* __restrict__ rdenom) {
    int p = blockIdx.x * 256 + threadIdx.x;
    if (p >= NPIX4) return;
    float4 m = {-3.4e38f, -3.4e38f, -3.4e38f, -3.4e38f};
    for (int d = 0; d < DD; ++d) {
        float4 v = in[(size_t)d * NPIX4 + p];
        m.x = fmaxf(m.x, -v.x); m.y = fmaxf(m.y, -v.y);
        m.z = fmaxf(m.z, -v.z); m.w = fmaxf(m.w, -v.w);
    }
    float4 sum = {0.f, 0.f, 0.f, 0.f};
    for (int d = 0; d < DD; ++d) {
        float4 v = in[(size_t)d * NPIX4 + p];
        float4 e;
        e.x = __expf(-v.x - m.x); e.y = __expf(-v.y - m.y);
        e.z = __expf(-v.z - m.z); e.w = __expf(-v.w - m.w);
        sum.x += e.x; sum.y += e.y; sum.z += e.z; sum.w += e.w;
        out[(size_t)d * NPIX4 + p] = e;
    }
    float4 r;
    r.x = 1.0f / sum.x; r.y = 1.0f / sum.y; r.z = 1.0f / sum.z; r.w = 1.0f / sum.w;
    rdenom[p] = r;
}

// ---------------- fused L1-normalize + disparity expectation (float4)
__global__ void final_kernel(const float4* __restrict__ p, float4* __restrict__ out) {
    int q = blockIdx.x * 256 + threadIdx.x;
    if (q >= NPIX4) return;
    float4 A = {0.f, 0.f, 0.f, 0.f}, S = {0.f, 0.f, 0.f, 0.f};
    for (int d = 0; d < DD; ++d) {
        float4 v = p[(size_t)d * NPIX4 + q];
        float fd = (float)d;
        A.x += v.x * fd; A.y += v.y * fd; A.z += v.z * fd; A.w += v.w * fd;
        S.x += fabsf(v.x); S.y += fabsf(v.y); S.z += fabsf(v.z); S.w += fabsf(v.w);
    }
    float4 r;
    r.x = A.x / fmaxf(S.x, 1e-12f);
    r.y = A.y / fmaxf(S.y, 1e-12f);
    r.z = A.z / fmaxf(S.z, 1e-12f);
    r.w = A.w / fmaxf(S.w, 1e-12f);
    out[q] = r;
}

extern "C" void kernel_launch(void* const* d_in, const int* in_sizes, int n_in,
                              void* d_out, int out_size, void* d_ws, size_t ws_size,
                              hipStream_t stream) {
    const float* x    = (const float*)d_in[0];
    const float* lg1  = (const float*)d_in[1];
    const float* lg2  = (const float*)d_in[2];
    const float* cw   = (const float*)d_in[3];
    float* out = (float*)d_out;

    float* ws   = (float*)d_ws;
    float* buf0 = ws;
    float* buf1 = buf0 + NVOL;
    float* cost = buf1 + NVOL;
    float* inv1 = cost + NCOST;
    float* inv2 = inv1 + NPIX;
    float* rden = inv2 + NPIX;

    // 1. conv3d
    conv3d_kernel<<<dim3(W0 / 64, H0 / 4, D0), dim3(64, 4), 0, stream>>>(x, cw, cost);
    // 2. guidance inverse L1 norms
    invnorm_kernel<<<(NPIX4 + 255) / 256, 256, 0, stream>>>((const float4*)lg1, (float4*)inv1);
    invnorm_kernel<<<(NPIX4 + 255) / 256, 256, 0, stream>>>((const float4*)lg2, (float4*)inv2);
    // 3. trilinear upsample
    resize_kernel<<<(int)((NVOL + 255) / 256), 256, 0, stream>>>(cost, buf0);
    // 4. LGA x2 with lg1
    lga_tiled_kernel<<<dim3(WW / TW, HH / TH), NTHR, 0, stream>>>(buf0, buf1, lg1, inv1, nullptr);
    lga_tiled_kernel<<<dim3(WW / TW, HH / TH), NTHR, 0, stream>>>(buf1, buf0, lg1, inv1, nullptr);
    // 5. softmax over d (unnormalized; denominator folded into next LGA's staging)
    softmax_kernel<<<(NPIX4 + 255) / 256, 256, 0, stream>>>((const float4*)buf0, (float4*)buf1, (float4*)rden);
    // 6. LGA x2 with lg2 (first applies softmax recip at source pixels)
    lga_tiled_kernel<<<dim3(WW / TW, HH / TH), NTHR, 0, stream>>>(buf1, buf0, lg2, inv2, rden);
    lga_tiled_kernel<<<dim3(WW / TW, HH / TH), NTHR, 0, stream>>>(buf0, buf1, lg2, inv2, nullptr);
    // 7. normalize + expectation
    final_kernel<<<(NPIX4 + 255) / 256, 256, 0, stream>>>((const float4*)buf1, (float4*)out);
}

// Round 4
// 1373.757 us; speedup vs baseline: 7.4236x; 1.2696x over previous
//
#include <hip/hip_runtime.h>
#include <hip/hip_bf16.h>
#include <math.h>

#define C_IN   32
#define D0     64
#define H0     96
#define W0     192
#define DD     193
#define HH     288
#define WW     576
#define NPIX   (HH*WW)            // 165888
#define NPIX4  (NPIX/4)           // 41472
#define NVOL   ((size_t)DD*NPIX)  // 32,016,384
#define NCOST  (D0*H0*W0)         // 1,179,648

// ---------------- LDS-tiled conv3d: x(32,64,96,192) * w(32,3,3,3) -> cost(64,96,192), pad=1
// Block: 256 threads = 64(w) x 4(h) outputs, 8-deep z-chunk held in registers.
// Per channel: stage 10 z-slices of the 6x66 spatial halo into LDS (double-buffered
// across channels, 1 sync/channel), 9 LDS tap reads + 27 FMAs per slice per thread.
#define CZC   8
#define CSL   (CZC + 2)        // 10 slices (z-halo)
#define CROWS 6
#define CCOLS 66
#define CCELL (CROWS * CCOLS)  // 396

__global__ __launch_bounds__(256)
void conv3d_tiled_kernel(const float* __restrict__ x,
                         const float* __restrict__ w,
                         float* __restrict__ cost) {
    __shared__ float sb[2][CSL][CCELL];
    const int tid = threadIdx.x;
    const int tx = tid & 63, ty = tid >> 6;
    const int wb = blockIdx.x * 64, hb = blockIdx.y * 4, z0 = blockIdx.z * CZC;

    float acc[CZC];
    #pragma unroll
    for (int i = 0; i < CZC; ++i) acc[i] = 0.f;

    // staging cell for this thread: cell tid (all) and tid+256 (tid<140)
    const int r0 = tid / CCOLS, q0 = tid - r0 * CCOLS;
    const int c1 = tid + 256;
    const int r1 = c1 / CCOLS, q1 = c1 - r1 * CCOLS;
    const bool has1 = (c1 < CCELL);
    const int hh0 = hb - 1 + r0, ww0 = wb - 1 + q0;
    const int hh1 = hb - 1 + r1, ww1 = wb - 1 + q1;
    const bool vs0 = (unsigned)hh0 < (unsigned)H0 && (unsigned)ww0 < (unsigned)W0;
    const bool vs1 = has1 && (unsigned)hh1 < (unsigned)H0 && (unsigned)ww1 < (unsigned)W0;
    const size_t po0 = vs0 ? (size_t)hh0 * W0 + ww0 : 0;
    const size_t po1 = vs1 ? (size_t)hh1 * W0 + ww1 : 0;

    #define STAGE(b, ci)                                                        \
    {                                                                           \
        const float* xc = x + (size_t)(ci) * (D0 * H0 * W0);                    \
        _Pragma("unroll")                                                       \
        for (int sl = 0; sl < CSL; ++sl) {                                      \
            int zz = z0 - 1 + sl;                                               \
            bool vz = (unsigned)zz < (unsigned)D0;                              \
            const float* xz = xc + (size_t)zz * (H0 * W0);                      \
            sb[b][sl][tid] = (vz && vs0) ? xz[po0] : 0.f;                       \
            if (has1) sb[b][sl][c1] = (vz && vs1) ? xz[po1] : 0.f;              \
        }                                                                       \
    }

    STAGE(0, 0);
    __syncthreads();

    for (int ci = 0; ci < C_IN; ++ci) {
        const int b = ci & 1;
        if (ci + 1 < C_IN) STAGE(b ^ 1, ci + 1);

        const float* wc = w + ci * 27;
        float wr[27];
        #pragma unroll
        for (int t = 0; t < 27; ++t) wr[t] = wc[t];

        #pragma unroll
        for (int sl = 0; sl < CSL; ++sl) {
            float tap[9];
            #pragma unroll
            for (int i = 0; i < 3; ++i)
                #pragma unroll
                for (int j = 0; j < 3; ++j)
                    tap[i * 3 + j] = sb[b][sl][(ty + i) * CCOLS + tx + j];
            // slice zz=z0-1+sl contributes: kd=0 -> acc[sl], kd=1 -> acc[sl-1], kd=2 -> acc[sl-2]
            if (sl < CZC) {
                float c = 0.f;
                #pragma unroll
                for (int t = 0; t < 9; ++t) c += wr[t] * tap[t];
                acc[sl] += c;
            }
            if (sl >= 1 && sl - 1 < CZC) {
                float c = 0.f;
                #pragma unroll
                for (int t = 0; t < 9; ++t) c += wr[9 + t] * tap[t];
                acc[sl - 1] += c;
            }
            if (sl >= 2) {
                float c = 0.f;
                #pragma unroll
                for (int t = 0; t < 9; ++t) c += wr[18 + t] * tap[t];
                acc[sl - 2] += c;
            }
        }
        __syncthreads();
    }
    #undef STAGE

    #pragma unroll
    for (int i = 0; i < CZC; ++i)
        cost[((size_t)(z0 + i) * H0 + (hb + ty)) * W0 + (wb + tx)] = acc[i];
}

// ---------------- per-pixel 1/L1-norm over 75 guidance channels (float4)
__global__ void invnorm_kernel(const float4* __restrict__ lg, float4* __restrict__ inv) {
    int p = blockIdx.x * 256 + threadIdx.x;
    if (p >= NPIX4) return;
    float4 s = {0.f, 0.f, 0.f, 0.f};
    for (int c = 0; c < 75; ++c) {
        float4 v = lg[(size_t)c * NPIX4 + p];
        s.x += fabsf(v.x); s.y += fabsf(v.y); s.z += fabsf(v.z); s.w += fabsf(v.w);
    }
    float4 r;
    r.x = 1.0f / fmaxf(s.x, 1e-12f);
    r.y = 1.0f / fmaxf(s.y, 1e-12f);
    r.z = 1.0f / fmaxf(s.z, 1e-12f);
    r.w = 1.0f / fmaxf(s.w, 1e-12f);
    inv[p] = r;
}

// ---------------- trilinear resize cost(64,96,192) -> out(193,288,576)
__global__ void resize_kernel(const float* __restrict__ cost, float* __restrict__ out) {
    size_t idx = (size_t)blockIdx.x * 256 + threadIdx.x;
    if (idx >= NVOL) return;
    int w = (int)(idx % WW);
    int t = (int)(idx / WW);
    int h = t % HH;
    int d = t / HH;

    float sd = fminf(fmaxf((d + 0.5f) * (64.0f / 193.0f) - 0.5f, 0.0f), 63.0f);
    int d0 = (int)floorf(sd); int d1 = min(d0 + 1, 63); float fd = sd - (float)d0;
    float sh = fminf(fmaxf((h + 0.5f) * (96.0f / 288.0f) - 0.5f, 0.0f), 95.0f);
    int h0 = (int)floorf(sh); int h1 = min(h0 + 1, 95); float fh = sh - (float)h0;
    float sw = fminf(fmaxf((w + 0.5f) * (192.0f / 576.0f) - 0.5f, 0.0f), 191.0f);
    int w0 = (int)floorf(sw); int w1 = min(w0 + 1, 191); float fw = sw - (float)w0;

    #define CV(dz, hy, wx) cost[((size_t)(dz) * H0 + (hy)) * W0 + (wx)]
    float v000 = CV(d0, h0, w0), v001 = CV(d0, h0, w1);
    float v010 = CV(d0, h1, w0), v011 = CV(d0, h1, w1);
    float v100 = CV(d1, h0, w0), v101 = CV(d1, h0, w1);
    float v110 = CV(d1, h1, w0), v111 = CV(d1, h1, w1);
    #undef CV
    float a = v000 * (1.f - fw) + v001 * fw;
    float b = v010 * (1.f - fw) + v011 * fw;
    float c = v100 * (1.f - fw) + v101 * fw;
    float e = v110 * (1.f - fw) + v111 * fw;
    float lo = a * (1.f - fh) + b * fh;
    float hi = c * (1.f - fh) + e * fh;
    out[idx] = lo * (1.f - fd) + hi * fd;
}

// ---------------- LDS-tiled LGA pass
#define TW 64
#define TH 8
#define HWT 68
#define HHT 12
#define NCELL (HWT*HHT)   // 816
#define NTHR 512

__global__ __launch_bounds__(NTHR)
void lga_tiled_kernel(const float* __restrict__ in, float* __restrict__ out,
                      const float* __restrict__ g, const float* __restrict__ inv,
                      const float* __restrict__ inscale) {
    __shared__ float sbuf[2][NCELL];
    const int tid = threadIdx.x;
    const int tx = tid & 63, ty = tid >> 6;
    const int wb = blockIdx.x * TW, hb = blockIdx.y * TH;
    const int pix = (hb + ty) * WW + (wb + tx);

    const int c0 = tid, c1 = tid + NTHR;
    const bool has1 = (c1 < NCELL);
    int r0 = c0 / HWT, q0 = c0 - r0 * HWT;
    int hh0 = hb - 2 + r0, ww0 = wb - 2 + q0;
    const bool v0 = (unsigned)hh0 < (unsigned)HH && (unsigned)ww0 < (unsigned)WW;
    const size_t off0 = v0 ? (size_t)hh0 * WW + ww0 : 0;
    const float is0 = (inscale != nullptr && v0) ? inscale[off0] : 1.0f;
    int r1 = c1 / HWT, q1 = c1 - r1 * HWT;
    int hh1 = hb - 2 + r1, ww1 = wb - 2 + q1;
    const bool v1 = has1 && (unsigned)hh1 < (unsigned)HH && (unsigned)ww1 < (unsigned)WW;
    const size_t off1 = v1 ? (size_t)hh1 * WW + ww1 : 0;
    const float is1 = (inscale != nullptr && v1) ? inscale[off1] : 1.0f;

    const float s = inv[pix];
    float g0[25], g1[25], g2[25];
    #pragma unroll
    for (int c = 0; c < 25; ++c) g0[c] = g[(size_t)c * NPIX + pix] * s;
    #pragma unroll
    for (int c = 0; c < 25; ++c) g1[c] = g[(size_t)(25 + c) * NPIX + pix] * s;
    #pragma unroll
    for (int c = 0; c < 25; ++c) g2[c] = g[(size_t)(50 + c) * NPIX + pix] * s;

    {
        sbuf[0][c0] = v0 ? in[off0] * is0 : 0.0f;
        if (has1) sbuf[0][c1] = v1 ? in[off1] * is1 : 0.0f;
    }

    float accA = 0.f, accB = 0.f;
    for (int e = 0; e < DD; ++e) {
        __syncthreads();
        if (e + 1 < DD) {
            const float* nsl = in + (size_t)(e + 1) * NPIX;
            float a = v0 ? nsl[off0] * is0 : 0.0f;
            float b = v1 ? nsl[off1] * is1 : 0.0f;
            float* nb = sbuf[(e + 1) & 1];
            nb[c0] = a;
            if (has1) nb[c1] = b;
        }
        const float* cur = sbuf[e & 1];
        float cc0 = 0.f, cc1 = 0.f, cc2 = 0.f;
        #pragma unroll
        for (int i = 0; i < 5; ++i) {
            const float* row = cur + (ty + i) * HWT + tx;
            #pragma unroll
            for (int j = 0; j < 5; ++j) {
                float v = row[j];
                cc0 += g0[i * 5 + j] * v;
                cc1 += g1[i * 5 + j] * v;
                cc2 += g2[i * 5 + j] * v;
            }
        }
        float rr = accA + cc2;
        if (e >= 1) out[(size_t)(e - 1) * NPIX + pix] = rr;
        accA = accB + cc1;
        accB = cc0;
    }
    out[(size_t)(DD - 1) * NPIX + pix] = accA;
}

// ---------------- softmax over d: write unnormalized exp + recip-sum (float4)
__global__ void softmax_kernel(const float4* __restrict__ in, float4* __restrict__ out,
                               float4* __restrict__ rdenom) {
    int p = blockIdx.x * 256 + threadIdx.x;
    if (p >= NPIX4) return;
    float4 m = {-3.4e38f, -3.4e38f, -3.4e38f, -3.4e38f};
    for (int d = 0; d < DD; ++d) {
        float4 v = in[(size_t)d * NPIX4 + p];
        m.x = fmaxf(m.x, -v.x); m.y = fmaxf(m.y, -v.y);
        m.z = fmaxf(m.z, -v.z); m.w = fmaxf(m.w, -v.w);
    }
    float4 sum = {0.f, 0.f, 0.f, 0.f};
    for (int d = 0; d < DD; ++d) {
        float4 v = in[(size_t)d * NPIX4 + p];
        float4 e;
        e.x = __expf(-v.x - m.x); e.y = __expf(-v.y - m.y);
        e.z = __expf(-v.z - m.z); e.w = __expf(-v.w - m.w);
        sum.x += e.x; sum.y += e.y; sum.z += e.z; sum.w += e.w;
        out[(size_t)d * NPIX4 + p] = e;
    }
    float4 r;
    r.x = 1.0f / sum.x; r.y = 1.0f / sum.y; r.z = 1.0f / sum.z; r.w = 1.0f / sum.w;
    rdenom[p] = r;
}

// ---------------- fused L1-normalize + disparity expectation (float4)
__global__ void final_kernel(const float4* __restrict__ p, float4* __restrict__ out) {
    int q = blockIdx.x * 256 + threadIdx.x;
    if (q >= NPIX4) return;
    float4 A = {0.f, 0.f, 0.f, 0.f}, S = {0.f, 0.f, 0.f, 0.f};
    for (int d = 0; d < DD; ++d) {
        float4 v = p[(size_t)d * NPIX4 + q];
        float fd = (float)d;
        A.x += v.x * fd; A.y += v.y * fd; A.z += v.z * fd; A.w += v.w * fd;
        S.x += fabsf(v.x); S.y += fabsf(v.y); S.z += fabsf(v.z); S.w += fabsf(v.w);
    }
    float4 r;
    r.x = A.x / fmaxf(S.x, 1e-12f);
    r.y = A.y / fmaxf(S.y, 1e-12f);
    r.z = A.z / fmaxf(S.z, 1e-12f);
    r.w = A.w / fmaxf(S.w, 1e-12f);
    out[q] = r;
}

extern "C" void kernel_launch(void* const* d_in, const int* in_sizes, int n_in,
                              void* d_out, int out_size, void* d_ws, size_t ws_size,
                              hipStream_t stream) {
    const float* x    = (const float*)d_in[0];
    const float* lg1  = (const float*)d_in[1];
    const float* lg2  = (const float*)d_in[2];
    const float* cw   = (const float*)d_in[3];
    float* out = (float*)d_out;

    float* ws   = (float*)d_ws;
    float* buf0 = ws;
    float* buf1 = buf0 + NVOL;
    float* cost = buf1 + NVOL;
    float* inv1 = cost + NCOST;
    float* inv2 = inv1 + NPIX;
    float* rden = inv2 + NPIX;

    // 1. conv3d (LDS-tiled, z-chunked)
    conv3d_tiled_kernel<<<dim3(W0 / 64, H0 / 4, D0 / CZC), 256, 0, stream>>>(x, cw, cost);
    // 2. guidance inverse L1 norms
    invnorm_kernel<<<(NPIX4 + 255) / 256, 256, 0, stream>>>((const float4*)lg1, (float4*)inv1);
    invnorm_kernel<<<(NPIX4 + 255) / 256, 256, 0, stream>>>((const float4*)lg2, (float4*)inv2);
    // 3. trilinear upsample
    resize_kernel<<<(int)((NVOL + 255) / 256), 256, 0, stream>>>(cost, buf0);
    // 4. LGA x2 with lg1
    lga_tiled_kernel<<<dim3(WW / TW, HH / TH), NTHR, 0, stream>>>(buf0, buf1, lg1, inv1, nullptr);
    lga_tiled_kernel<<<dim3(WW / TW, HH / TH), NTHR, 0, stream>>>(buf1, buf0, lg1, inv1, nullptr);
    // 5. softmax over d (unnormalized; denominator folded into next LGA's staging)
    softmax_kernel<<<(NPIX4 + 255) / 256, 256, 0, stream>>>((const float4*)buf0, (float4*)buf1, (float4*)rden);
    // 6. LGA x2 with lg2 (first applies softmax recip at source pixels)
    lga_tiled_kernel<<<dim3(WW / TW, HH / TH), NTHR, 0, stream>>>(buf1, buf0, lg2, inv2, rden);
    lga_tiled_kernel<<<dim3(WW / TW, HH / TH), NTHR, 0, stream>>>(buf0, buf1, lg2, inv2, nullptr);
    // 7. normalize + expectation
    final_kernel<<<(NPIX4 + 255) / 256, 256, 0, stream>>>((const float4*)buf1, (float4*)out);
}

// Round 5
// 1202.137 us; speedup vs baseline: 8.4834x; 1.1428x over previous
//
#include <hip/hip_runtime.h>
#include <hip/hip_bf16.h>
#include <math.h>

#define C_IN   32
#define D0     64
#define H0     96
#define W0     192
#define DD     193
#define HH     288
#define WW     576
#define NPIX   (HH*WW)            // 165888
#define NPIX4  (NPIX/4)           // 41472
#define NVOL   ((size_t)DD*NPIX)  // 32,016,384
#define NCOST  (D0*H0*W0)         // 1,179,648
#define NCOST4 (NCOST/4)          // 294912

// ---------------- LDS-tiled conv3d, channel-split x4
// x(32,64,96,192) * w(32,3,3,3) -> 4 partial volumes (64,96,192), pad=1.
// Block: 256 threads = 64(w) x 4(h) outputs, 8-deep z-chunk in registers,
// 8 input channels per block (part = blockIdx.z>>3). Per channel: stage 10
// z-slices of the 6x66 spatial halo into LDS via float4 interior + scalar
// edges (row stride 72, interior at word 4 => 16B-aligned ds_write_b128),
// double-buffered, 1 sync/channel.
#define CZC   8
#define CSL   (CZC + 2)        // 10 slices (z-halo)
#define CROWS 6
#define CSTR  72               // padded row stride (words); cell m at idx m+3

__global__ __launch_bounds__(256)
void conv3d_split_kernel(const float* __restrict__ x,
                         const float* __restrict__ w,
                         float* __restrict__ partial) {
    __shared__ __align__(16) float sb[2][CSL][CROWS][CSTR];
    const int tid = threadIdx.x;
    const int tx = tid & 63, ty = tid >> 6;
    const int wb = blockIdx.x * 64, hb = blockIdx.y * 4;
    const int zc = blockIdx.z & 7, part = blockIdx.z >> 3;
    const int z0 = zc * CZC;
    const int cbase = part * 8;

    float acc[CZC];
    #pragma unroll
    for (int i = 0; i < CZC; ++i) acc[i] = 0.f;

    // --- staging task decode (hoisted): vector tasks t in [0,960), edge tasks tid<120
    // vec: sl=t/96, r=(t%96)>>4, v=t&15 -> global (zz, hh, wb+4v), LDS [sl][r][4+4v]
    // edge: sl=tid/12, r=(tid%12)>>1, side=tid&1 -> ww = side? wb+64 : wb-1, LDS idx side?68:3
    const float4 f4zero = {0.f, 0.f, 0.f, 0.f};

    #define STAGE(b, ci)                                                          \
    {                                                                             \
        const float* xc = x + (size_t)(ci) * (D0 * H0 * W0);                      \
        _Pragma("unroll")                                                         \
        for (int t0 = 0; t0 < 4; ++t0) {                                          \
            int t = t0 * 256 + tid;                                               \
            if (t < 960) {                                                        \
                int sl = t / 96; int rem = t - sl * 96;                           \
                int r = rem >> 4, v = rem & 15;                                   \
                int zz = z0 - 1 + sl, hh = hb - 1 + r;                            \
                bool ok = (unsigned)zz < (unsigned)D0 && (unsigned)hh < (unsigned)H0; \
                float4 val = ok ? *(const float4*)(xc + ((size_t)zz * H0 + hh) * W0 + wb + 4 * v) \
                                : f4zero;                                         \
                *(float4*)&sb[b][sl][r][4 + 4 * v] = val;                         \
            }                                                                     \
        }                                                                         \
        if (tid < 120) {                                                          \
            int sl = tid / 12; int e = tid - sl * 12;                             \
            int r = e >> 1, side = e & 1;                                         \
            int zz = z0 - 1 + sl, hh = hb - 1 + r;                                \
            int ww = side ? wb + 64 : wb - 1;                                     \
            bool ok = (unsigned)zz < (unsigned)D0 && (unsigned)hh < (unsigned)H0  \
                      && (unsigned)ww < (unsigned)W0;                             \
            sb[b][sl][r][side ? 68 : 3] = ok ? xc[((size_t)zz * H0 + hh) * W0 + ww] : 0.f; \
        }                                                                         \
    }

    STAGE(0, cbase);
    __syncthreads();

    for (int c = 0; c < 8; ++c) {
        const int b = c & 1;
        if (c + 1 < 8) STAGE(b ^ 1, cbase + c + 1);

        const float* wc = w + (cbase + c) * 27;
        float wr[27];
        #pragma unroll
        for (int t = 0; t < 27; ++t) wr[t] = wc[t];

        #pragma unroll
        for (int sl = 0; sl < CSL; ++sl) {
            float tap[9];
            #pragma unroll
            for (int i = 0; i < 3; ++i)
                #pragma unroll
                for (int j = 0; j < 3; ++j)
                    tap[i * 3 + j] = sb[b][sl][ty + i][tx + 3 + j];
            // slice zz=z0-1+sl: kd=0 -> acc[sl], kd=1 -> acc[sl-1], kd=2 -> acc[sl-2]
            if (sl < CZC) {
                float cs = 0.f;
                #pragma unroll
                for (int t = 0; t < 9; ++t) cs += wr[t] * tap[t];
                acc[sl] += cs;
            }
            if (sl >= 1 && sl - 1 < CZC) {
                float cs = 0.f;
                #pragma unroll
                for (int t = 0; t < 9; ++t) cs += wr[9 + t] * tap[t];
                acc[sl - 1] += cs;
            }
            if (sl >= 2) {
                float cs = 0.f;
                #pragma unroll
                for (int t = 0; t < 9; ++t) cs += wr[18 + t] * tap[t];
                acc[sl - 2] += cs;
            }
        }
        __syncthreads();
    }
    #undef STAGE

    float* po = partial + (size_t)part * NCOST;
    #pragma unroll
    for (int i = 0; i < CZC; ++i)
        po[((size_t)(z0 + i) * H0 + (hb + ty)) * W0 + (wb + tx)] = acc[i];
}

// ---------------- combine 4 partials -> cost (float4)
__global__ void combine_kernel(const float4* __restrict__ partial, float4* __restrict__ cost) {
    int i = blockIdx.x * 256 + threadIdx.x;
    if (i >= NCOST4) return;
    float4 a = partial[i];
    float4 b = partial[i + NCOST4];
    float4 c = partial[i + 2 * NCOST4];
    float4 d = partial[i + 3 * NCOST4];
    float4 r;
    r.x = a.x + b.x + c.x + d.x;
    r.y = a.y + b.y + c.y + d.y;
    r.z = a.z + b.z + c.z + d.z;
    r.w = a.w + b.w + c.w + d.w;
    cost[i] = r;
}

// ---------------- per-pixel 1/L1-norm over 75 guidance channels (float4)
__global__ void invnorm_kernel(const float4* __restrict__ lg, float4* __restrict__ inv) {
    int p = blockIdx.x * 256 + threadIdx.x;
    if (p >= NPIX4) return;
    float4 s = {0.f, 0.f, 0.f, 0.f};
    for (int c = 0; c < 75; ++c) {
        float4 v = lg[(size_t)c * NPIX4 + p];
        s.x += fabsf(v.x); s.y += fabsf(v.y); s.z += fabsf(v.z); s.w += fabsf(v.w);
    }
    float4 r;
    r.x = 1.0f / fmaxf(s.x, 1e-12f);
    r.y = 1.0f / fmaxf(s.y, 1e-12f);
    r.z = 1.0f / fmaxf(s.z, 1e-12f);
    r.w = 1.0f / fmaxf(s.w, 1e-12f);
    inv[p] = r;
}

// ---------------- trilinear resize cost(64,96,192) -> out(193,288,576)
__global__ void resize_kernel(const float* __restrict__ cost, float* __restrict__ out) {
    size_t idx = (size_t)blockIdx.x * 256 + threadIdx.x;
    if (idx >= NVOL) return;
    int w = (int)(idx % WW);
    int t = (int)(idx / WW);
    int h = t % HH;
    int d = t / HH;

    float sd = fminf(fmaxf((d + 0.5f) * (64.0f / 193.0f) - 0.5f, 0.0f), 63.0f);
    int d0 = (int)floorf(sd); int d1 = min(d0 + 1, 63); float fd = sd - (float)d0;
    float sh = fminf(fmaxf((h + 0.5f) * (96.0f / 288.0f) - 0.5f, 0.0f), 95.0f);
    int h0 = (int)floorf(sh); int h1 = min(h0 + 1, 95); float fh = sh - (float)h0;
    float sw = fminf(fmaxf((w + 0.5f) * (192.0f / 576.0f) - 0.5f, 0.0f), 191.0f);
    int w0 = (int)floorf(sw); int w1 = min(w0 + 1, 191); float fw = sw - (float)w0;

    #define CV(dz, hy, wx) cost[((size_t)(dz) * H0 + (hy)) * W0 + (wx)]
    float v000 = CV(d0, h0, w0), v001 = CV(d0, h0, w1);
    float v010 = CV(d0, h1, w0), v011 = CV(d0, h1, w1);
    float v100 = CV(d1, h0, w0), v101 = CV(d1, h0, w1);
    float v110 = CV(d1, h1, w0), v111 = CV(d1, h1, w1);
    #undef CV
    float a = v000 * (1.f - fw) + v001 * fw;
    float b = v010 * (1.f - fw) + v011 * fw;
    float c = v100 * (1.f - fw) + v101 * fw;
    float e = v110 * (1.f - fw) + v111 * fw;
    float lo = a * (1.f - fh) + b * fh;
    float hi = c * (1.f - fh) + e * fh;
    out[idx] = lo * (1.f - fd) + hi * fd;
}

// ---------------- LDS-tiled LGA pass
#define TW 64
#define TH 8
#define HWT 68
#define HHT 12
#define NCELL (HWT*HHT)   // 816
#define NTHR 512

__global__ __launch_bounds__(NTHR)
void lga_tiled_kernel(const float* __restrict__ in, float* __restrict__ out,
                      const float* __restrict__ g, const float* __restrict__ inv,
                      const float* __restrict__ inscale) {
    __shared__ float sbuf[2][NCELL];
    const int tid = threadIdx.x;
    const int tx = tid & 63, ty = tid >> 6;
    const int wb = blockIdx.x * TW, hb = blockIdx.y * TH;
    const int pix = (hb + ty) * WW + (wb + tx);

    const int c0 = tid, c1 = tid + NTHR;
    const bool has1 = (c1 < NCELL);
    int r0 = c0 / HWT, q0 = c0 - r0 * HWT;
    int hh0 = hb - 2 + r0, ww0 = wb - 2 + q0;
    const bool v0 = (unsigned)hh0 < (unsigned)HH && (unsigned)ww0 < (unsigned)WW;
    const size_t off0 = v0 ? (size_t)hh0 * WW + ww0 : 0;
    const float is0 = (inscale != nullptr && v0) ? inscale[off0] : 1.0f;
    int r1 = c1 / HWT, q1 = c1 - r1 * HWT;
    int hh1 = hb - 2 + r1, ww1 = wb - 2 + q1;
    const bool v1 = has1 && (unsigned)hh1 < (unsigned)HH && (unsigned)ww1 < (unsigned)WW;
    const size_t off1 = v1 ? (size_t)hh1 * WW + ww1 : 0;
    const float is1 = (inscale != nullptr && v1) ? inscale[off1] : 1.0f;

    const float s = inv[pix];
    float g0[25], g1[25], g2[25];
    #pragma unroll
    for (int c = 0; c < 25; ++c) g0[c] = g[(size_t)c * NPIX + pix] * s;
    #pragma unroll
    for (int c = 0; c < 25; ++c) g1[c] = g[(size_t)(25 + c) * NPIX + pix] * s;
    #pragma unroll
    for (int c = 0; c < 25; ++c) g2[c] = g[(size_t)(50 + c) * NPIX + pix] * s;

    {
        sbuf[0][c0] = v0 ? in[off0] * is0 : 0.0f;
        if (has1) sbuf[0][c1] = v1 ? in[off1] * is1 : 0.0f;
    }

    float accA = 0.f, accB = 0.f;
    for (int e = 0; e < DD; ++e) {
        __syncthreads();
        if (e + 1 < DD) {
            const float* nsl = in + (size_t)(e + 1) * NPIX;
            float a = v0 ? nsl[off0] * is0 : 0.0f;
            float b = v1 ? nsl[off1] * is1 : 0.0f;
            float* nb = sbuf[(e + 1) & 1];
            nb[c0] = a;
            if (has1) nb[c1] = b;
        }
        const float* cur = sbuf[e & 1];
        float cc0 = 0.f, cc1 = 0.f, cc2 = 0.f;
        #pragma unroll
        for (int i = 0; i < 5; ++i) {
            const float* row = cur + (ty + i) * HWT + tx;
            #pragma unroll
            for (int j = 0; j < 5; ++j) {
                float v = row[j];
                cc0 += g0[i * 5 + j] * v;
                cc1 += g1[i * 5 + j] * v;
                cc2 += g2[i * 5 + j] * v;
            }
        }
        float rr = accA + cc2;
        if (e >= 1) out[(size_t)(e - 1) * NPIX + pix] = rr;
        accA = accB + cc1;
        accB = cc0;
    }
    out[(size_t)(DD - 1) * NPIX + pix] = accA;
}

// ---------------- softmax over d: write unnormalized exp + recip-sum (float4)
__global__ void softmax_kernel(const float4* __restrict__ in, float4* __restrict__ out,
                               float4* __restrict__ rdenom) {
    int p = blockIdx.x * 256 + threadIdx.x;
    if (p >= NPIX4) return;
    float4 m = {-3.4e38f, -3.4e38f, -3.4e38f, -3.4e38f};
    for (int d = 0; d < DD; ++d) {
        float4 v = in[(size_t)d * NPIX4 + p];
        m.x = fmaxf(m.x, -v.x); m.y = fmaxf(m.y, -v.y);
        m.z = fmaxf(m.z, -v.z); m.w = fmaxf(m.w, -v.w);
    }
    float4 sum = {0.f, 0.f, 0.f, 0.f};
    for (int d = 0; d < DD; ++d) {
        float4 v = in[(size_t)d * NPIX4 + p];
        float4 e;
        e.x = __expf(-v.x - m.x); e.y = __expf(-v.y - m.y);
        e.z = __expf(-v.z - m.z); e.w = __expf(-v.w - m.w);
        sum.x += e.x; sum.y += e.y; sum.z += e.z; sum.w += e.w;
        out[(size_t)d * NPIX4 + p] = e;
    }
    float4 r;
    r.x = 1.0f / sum.x; r.y = 1.0f / sum.y; r.z = 1.0f / sum.z; r.w = 1.0f / sum.w;
    rdenom[p] = r;
}

// ---------------- fused L1-normalize + disparity expectation (float4)
__global__ void final_kernel(const float4* __restrict__ p, float4* __restrict__ out) {
    int q = blockIdx.x * 256 + threadIdx.x;
    if (q >= NPIX4) return;
    float4 A = {0.f, 0.f, 0.f, 0.f}, S = {0.f, 0.f, 0.f, 0.f};
    for (int d = 0; d < DD; ++d) {
        float4 v = p[(size_t)d * NPIX4 + q];
        float fd = (float)d;
        A.x += v.x * fd; A.y += v.y * fd; A.z += v.z * fd; A.w += v.w * fd;
        S.x += fabsf(v.x); S.y += fabsf(v.y); S.z += fabsf(v.z); S.w += fabsf(v.w);
    }
    float4 r;
    r.x = A.x / fmaxf(S.x, 1e-12f);
    r.y = A.y / fmaxf(S.y, 1e-12f);
    r.z = A.z / fmaxf(S.z, 1e-12f);
    r.w = A.w / fmaxf(S.w, 1e-12f);
    out[q] = r;
}

extern "C" void kernel_launch(void* const* d_in, const int* in_sizes, int n_in,
                              void* d_out, int out_size, void* d_ws, size_t ws_size,
                              hipStream_t stream) {
    const float* x    = (const float*)d_in[0];
    const float* lg1  = (const float*)d_in[1];
    const float* lg2  = (const float*)d_in[2];
    const float* cw   = (const float*)d_in[3];
    float* out = (float*)d_out;

    float* ws   = (float*)d_ws;
    float* buf0 = ws;
    float* buf1 = buf0 + NVOL;
    float* cost = buf1 + NVOL;
    float* inv1 = cost + NCOST;
    float* inv2 = inv1 + NPIX;
    float* rden = inv2 + NPIX;
    // conv partials (4 x NCOST) live in buf1's region; dead before lga#1 writes buf1
    float* partials = buf1;

    // 1. conv3d (channel-split x4) + combine
    conv3d_split_kernel<<<dim3(W0 / 64, H0 / 4, (D0 / CZC) * 4), 256, 0, stream>>>(x, cw, partials);
    combine_kernel<<<(NCOST4 + 255) / 256, 256, 0, stream>>>((const float4*)partials, (float4*)cost);
    // 2. guidance inverse L1 norms
    invnorm_kernel<<<(NPIX4 + 255) / 256, 256, 0, stream>>>((const float4*)lg1, (float4*)inv1);
    invnorm_kernel<<<(NPIX4 + 255) / 256, 256, 0, stream>>>((const float4*)lg2, (float4*)inv2);
    // 3. trilinear upsample
    resize_kernel<<<(int)((NVOL + 255) / 256), 256, 0, stream>>>(cost, buf0);
    // 4. LGA x2 with lg1
    lga_tiled_kernel<<<dim3(WW / TW, HH / TH), NTHR, 0, stream>>>(buf0, buf1, lg1, inv1, nullptr);
    lga_tiled_kernel<<<dim3(WW / TW, HH / TH), NTHR, 0, stream>>>(buf1, buf0, lg1, inv1, nullptr);
    // 5. softmax over d (unnormalized; denominator folded into next LGA's staging)
    softmax_kernel<<<(NPIX4 + 255) / 256, 256, 0, stream>>>((const float4*)buf0, (float4*)buf1, (float4*)rden);
    // 6. LGA x2 with lg2 (first applies softmax recip at source pixels)
    lga_tiled_kernel<<<dim3(WW / TW, HH / TH), NTHR, 0, stream>>>(buf1, buf0, lg2, inv2, rden);
    lga_tiled_kernel<<<dim3(WW / TW, HH / TH), NTHR, 0, stream>>>(buf0, buf1, lg2, inv2, nullptr);
    // 7. normalize + expectation
    final_kernel<<<(NPIX4 + 255) / 256, 256, 0, stream>>>((const float4*)buf1, (float4*)out);
}

// Round 6
// 1092.079 us; speedup vs baseline: 9.3384x; 1.1008x over previous
//
#include <hip/hip_runtime.h>
#include <hip/hip_bf16.h>
#include <math.h>

#define C_IN   32
#define D0     64
#define H0     96
#define W0     192
#define DD     193
#define HH     288
#define WW     576
#define NPIX   (HH*WW)            // 165888
#define NPIX4  (NPIX/4)           // 41472
#define NVOL   ((size_t)DD*NPIX)  // 32,016,384
#define NCOST  (D0*H0*W0)         // 1,179,648
#define NCOST4 (NCOST/4)          // 294912

// ---------------- LDS-tiled conv3d, channel-split x4
#define CZC   8
#define CSL   (CZC + 2)        // 10 slices (z-halo)
#define CROWS 6
#define CSTR  72               // padded row stride (words)

__global__ __launch_bounds__(256)
void conv3d_split_kernel(const float* __restrict__ x,
                         const float* __restrict__ w,
                         float* __restrict__ partial) {
    __shared__ __align__(16) float sb[2][CSL][CROWS][CSTR];
    const int tid = threadIdx.x;
    const int tx = tid & 63, ty = tid >> 6;
    const int wb = blockIdx.x * 64, hb = blockIdx.y * 4;
    const int zc = blockIdx.z & 7, part = blockIdx.z >> 3;
    const int z0 = zc * CZC;
    const int cbase = part * 8;

    float acc[CZC];
    #pragma unroll
    for (int i = 0; i < CZC; ++i) acc[i] = 0.f;

    const float4 f4zero = {0.f, 0.f, 0.f, 0.f};

    #define STAGE(b, ci)                                                          \
    {                                                                             \
        const float* xc = x + (size_t)(ci) * (D0 * H0 * W0);                      \
        _Pragma("unroll")                                                         \
        for (int t0 = 0; t0 < 4; ++t0) {                                          \
            int t = t0 * 256 + tid;                                               \
            if (t < 960) {                                                        \
                int sl = t / 96; int rem = t - sl * 96;                           \
                int r = rem >> 4, v = rem & 15;                                   \
                int zz = z0 - 1 + sl, hh = hb - 1 + r;                            \
                bool ok = (unsigned)zz < (unsigned)D0 && (unsigned)hh < (unsigned)H0; \
                float4 val = ok ? *(const float4*)(xc + ((size_t)zz * H0 + hh) * W0 + wb + 4 * v) \
                                : f4zero;                                         \
                *(float4*)&sb[b][sl][r][4 + 4 * v] = val;                         \
            }                                                                     \
        }                                                                         \
        if (tid < 120) {                                                          \
            int sl = tid / 12; int e = tid - sl * 12;                             \
            int r = e >> 1, side = e & 1;                                         \
            int zz = z0 - 1 + sl, hh = hb - 1 + r;                                \
            int ww = side ? wb + 64 : wb - 1;                                     \
            bool ok = (unsigned)zz < (unsigned)D0 && (unsigned)hh < (unsigned)H0  \
                      && (unsigned)ww < (unsigned)W0;                             \
            sb[b][sl][r][side ? 68 : 3] = ok ? xc[((size_t)zz * H0 + hh) * W0 + ww] : 0.f; \
        }                                                                         \
    }

    STAGE(0, cbase);
    __syncthreads();

    for (int c = 0; c < 8; ++c) {
        const int b = c & 1;
        if (c + 1 < 8) STAGE(b ^ 1, cbase + c + 1);

        const float* wc = w + (cbase + c) * 27;
        float wr[27];
        #pragma unroll
        for (int t = 0; t < 27; ++t) wr[t] = wc[t];

        #pragma unroll
        for (int sl = 0; sl < CSL; ++sl) {
            float tap[9];
            #pragma unroll
            for (int i = 0; i < 3; ++i)
                #pragma unroll
                for (int j = 0; j < 3; ++j)
                    tap[i * 3 + j] = sb[b][sl][ty + i][tx + 3 + j];
            if (sl < CZC) {
                float cs = 0.f;
                #pragma unroll
                for (int t = 0; t < 9; ++t) cs += wr[t] * tap[t];
                acc[sl] += cs;
            }
            if (sl >= 1 && sl - 1 < CZC) {
                float cs = 0.f;
                #pragma unroll
                for (int t = 0; t < 9; ++t) cs += wr[9 + t] * tap[t];
                acc[sl - 1] += cs;
            }
            if (sl >= 2) {
                float cs = 0.f;
                #pragma unroll
                for (int t = 0; t < 9; ++t) cs += wr[18 + t] * tap[t];
                acc[sl - 2] += cs;
            }
        }
        __syncthreads();
    }
    #undef STAGE

    float* po = partial + (size_t)part * NCOST;
    #pragma unroll
    for (int i = 0; i < CZC; ++i)
        po[((size_t)(z0 + i) * H0 + (hb + ty)) * W0 + (wb + tx)] = acc[i];
}

// ---------------- combine 4 partials -> cost (float4)
__global__ void combine_kernel(const float4* __restrict__ partial, float4* __restrict__ cost) {
    int i = blockIdx.x * 256 + threadIdx.x;
    if (i >= NCOST4) return;
    float4 a = partial[i];
    float4 b = partial[i + NCOST4];
    float4 c = partial[i + 2 * NCOST4];
    float4 d = partial[i + 3 * NCOST4];
    float4 r;
    r.x = a.x + b.x + c.x + d.x;
    r.y = a.y + b.y + c.y + d.y;
    r.z = a.z + b.z + c.z + d.z;
    r.w = a.w + b.w + c.w + d.w;
    cost[i] = r;
}

// ---------------- per-pixel 1/L1-norm over 75 guidance channels (float4)
__global__ void invnorm_kernel(const float4* __restrict__ lg, float4* __restrict__ inv) {
    int p = blockIdx.x * 256 + threadIdx.x;
    if (p >= NPIX4) return;
    float4 s = {0.f, 0.f, 0.f, 0.f};
    for (int c = 0; c < 75; ++c) {
        float4 v = lg[(size_t)c * NPIX4 + p];
        s.x += fabsf(v.x); s.y += fabsf(v.y); s.z += fabsf(v.z); s.w += fabsf(v.w);
    }
    float4 r;
    r.x = 1.0f / fmaxf(s.x, 1e-12f);
    r.y = 1.0f / fmaxf(s.y, 1e-12f);
    r.z = 1.0f / fmaxf(s.z, 1e-12f);
    r.w = 1.0f / fmaxf(s.w, 1e-12f);
    inv[p] = r;
}

// ---------------- trilinear resize cost(64,96,192) -> out(193,288,576)
__global__ void resize_kernel(const float* __restrict__ cost, float* __restrict__ out) {
    size_t idx = (size_t)blockIdx.x * 256 + threadIdx.x;
    if (idx >= NVOL) return;
    int w = (int)(idx % WW);
    int t = (int)(idx / WW);
    int h = t % HH;
    int d = t / HH;

    float sd = fminf(fmaxf((d + 0.5f) * (64.0f / 193.0f) - 0.5f, 0.0f), 63.0f);
    int d0 = (int)floorf(sd); int d1 = min(d0 + 1, 63); float fd = sd - (float)d0;
    float sh = fminf(fmaxf((h + 0.5f) * (96.0f / 288.0f) - 0.5f, 0.0f), 95.0f);
    int h0 = (int)floorf(sh); int h1 = min(h0 + 1, 95); float fh = sh - (float)h0;
    float sw = fminf(fmaxf((w + 0.5f) * (192.0f / 576.0f) - 0.5f, 0.0f), 191.0f);
    int w0 = (int)floorf(sw); int w1 = min(w0 + 1, 191); float fw = sw - (float)w0;

    #define CV(dz, hy, wx) cost[((size_t)(dz) * H0 + (hy)) * W0 + (wx)]
    float v000 = CV(d0, h0, w0), v001 = CV(d0, h0, w1);
    float v010 = CV(d0, h1, w0), v011 = CV(d0, h1, w1);
    float v100 = CV(d1, h0, w0), v101 = CV(d1, h0, w1);
    float v110 = CV(d1, h1, w0), v111 = CV(d1, h1, w1);
    #undef CV
    float a = v000 * (1.f - fw) + v001 * fw;
    float b = v010 * (1.f - fw) + v011 * fw;
    float c = v100 * (1.f - fw) + v101 * fw;
    float e = v110 * (1.f - fw) + v111 * fw;
    float lo = a * (1.f - fh) + b * fh;
    float hi = c * (1.f - fh) + e * fh;
    out[idx] = lo * (1.f - fd) + hi * fd;
}

// ---------------- LDS-tiled LGA pass, d-split
// MODE 0: plain store. MODE 1: store exp(-v), atomic per-pixel sum into accS.
// MODE 2: no store; accumulate A=sum v*d, S=sum |v|, atomics into accA/accS.
#define TW 64
#define TH 8
#define HWT 68
#define HHT 12
#define NCELL (HWT*HHT)   // 816
#define NTHR 512
#define DCHUNK 25
#define NDCH  8           // ceil(193/25)

template<int MODE>
__global__ __launch_bounds__(NTHR, 4)
void lga_tiled_kernel(const float* __restrict__ in, float* __restrict__ out,
                      const float* __restrict__ g, const float* __restrict__ inv,
                      const float* __restrict__ inscale,
                      float* __restrict__ accAbuf, float* __restrict__ accSbuf) {
    __shared__ float sbuf[2][NCELL];
    const int tid = threadIdx.x;
    const int tx = tid & 63, ty = tid >> 6;
    const int wb = blockIdx.x * TW, hb = blockIdx.y * TH;
    const int pix = (hb + ty) * WW + (wb + tx);
    const int ds = blockIdx.z * DCHUNK;
    const int de = min(ds + DCHUNK, DD);
    const int e0 = max(ds - 1, 0);
    const int emax = min(de, DD - 1);

    const int c0 = tid, c1 = tid + NTHR;
    const bool has1 = (c1 < NCELL);
    int r0 = c0 / HWT, q0 = c0 - r0 * HWT;
    int hh0 = hb - 2 + r0, ww0 = wb - 2 + q0;
    const bool v0 = (unsigned)hh0 < (unsigned)HH && (unsigned)ww0 < (unsigned)WW;
    const size_t off0 = v0 ? (size_t)hh0 * WW + ww0 : 0;
    const float is0 = (inscale != nullptr && v0) ? inscale[off0] : 1.0f;
    int r1 = c1 / HWT, q1 = c1 - r1 * HWT;
    int hh1 = hb - 2 + r1, ww1 = wb - 2 + q1;
    const bool v1 = has1 && (unsigned)hh1 < (unsigned)HH && (unsigned)ww1 < (unsigned)WW;
    const size_t off1 = v1 ? (size_t)hh1 * WW + ww1 : 0;
    const float is1 = (inscale != nullptr && v1) ? inscale[off1] : 1.0f;

    const float s = inv[pix];
    float g0[25], g1[25], g2[25];
    #pragma unroll
    for (int c = 0; c < 25; ++c) g0[c] = g[(size_t)c * NPIX + pix] * s;
    #pragma unroll
    for (int c = 0; c < 25; ++c) g1[c] = g[(size_t)(25 + c) * NPIX + pix] * s;
    #pragma unroll
    for (int c = 0; c < 25; ++c) g2[c] = g[(size_t)(50 + c) * NPIX + pix] * s;

    {
        const float* sl = in + (size_t)e0 * NPIX;
        sbuf[e0 & 1][c0] = v0 ? sl[off0] * is0 : 0.0f;
        if (has1) sbuf[e0 & 1][c1] = v1 ? sl[off1] * is1 : 0.0f;
    }

    float accA = 0.f, accB = 0.f;
    float aloc = 0.f, sloc = 0.f;

    #define EMIT(n, val)                                                          \
    {                                                                             \
        if constexpr (MODE == 0) {                                                \
            out[(size_t)(n) * NPIX + pix] = (val);                                \
        } else if constexpr (MODE == 1) {                                         \
            float ev = __expf(-(val));                                            \
            out[(size_t)(n) * NPIX + pix] = ev;                                   \
            sloc += ev;                                                           \
        } else {                                                                  \
            aloc += (val) * (float)(n);                                           \
            sloc += fabsf(val);                                                   \
        }                                                                         \
    }

    for (int e = e0; e <= emax; ++e) {
        __syncthreads();
        if (e < emax) {
            const float* nsl = in + (size_t)(e + 1) * NPIX;
            float a = v0 ? nsl[off0] * is0 : 0.0f;
            float b = v1 ? nsl[off1] * is1 : 0.0f;
            float* nb = sbuf[(e + 1) & 1];
            nb[c0] = a;
            if (has1) nb[c1] = b;
        }
        const float* cur = sbuf[e & 1];
        float cc0 = 0.f, cc1 = 0.f, cc2 = 0.f;
        #pragma unroll
        for (int i = 0; i < 5; ++i) {
            const float* row = cur + (ty + i) * HWT + tx;
            #pragma unroll
            for (int j = 0; j < 5; ++j) {
                float v = row[j];
                cc0 += g0[i * 5 + j] * v;
                cc1 += g1[i * 5 + j] * v;
                cc2 += g2[i * 5 + j] * v;
            }
        }
        int n = e - 1;
        if (n >= ds && n < de) {
            float rr = accA + cc2;
            EMIT(n, rr);
        }
        accA = accB + cc1;
        accB = cc0;
    }
    if (de == DD) {
        EMIT(DD - 1, accA);  // slice DD is zero-pad: no c2 term
    }
    #undef EMIT

    if constexpr (MODE == 1) {
        atomicAdd(&accSbuf[pix], sloc);
    } else if constexpr (MODE == 2) {
        atomicAdd(&accAbuf[pix], aloc);
        atomicAdd(&accSbuf[pix], sloc);
    }
}

// ---------------- reciprocal in place (float4)
__global__ void rcp_kernel(float4* __restrict__ v) {
    int p = blockIdx.x * 256 + threadIdx.x;
    if (p >= NPIX4) return;
    float4 a = v[p];
    a.x = 1.0f / a.x; a.y = 1.0f / a.y; a.z = 1.0f / a.z; a.w = 1.0f / a.w;
    v[p] = a;
}

// ---------------- finish: out = A / max(S, eps) (float4)
__global__ void finish_kernel(const float4* __restrict__ A, const float4* __restrict__ S,
                              float4* __restrict__ out) {
    int p = blockIdx.x * 256 + threadIdx.x;
    if (p >= NPIX4) return;
    float4 a = A[p], s = S[p];
    float4 r;
    r.x = a.x / fmaxf(s.x, 1e-12f);
    r.y = a.y / fmaxf(s.y, 1e-12f);
    r.z = a.z / fmaxf(s.z, 1e-12f);
    r.w = a.w / fmaxf(s.w, 1e-12f);
    out[p] = r;
}

extern "C" void kernel_launch(void* const* d_in, const int* in_sizes, int n_in,
                              void* d_out, int out_size, void* d_ws, size_t ws_size,
                              hipStream_t stream) {
    const float* x    = (const float*)d_in[0];
    const float* lg1  = (const float*)d_in[1];
    const float* lg2  = (const float*)d_in[2];
    const float* cw   = (const float*)d_in[3];
    float* out = (float*)d_out;

    float* ws   = (float*)d_ws;
    float* buf0 = ws;
    float* buf1 = buf0 + NVOL;
    float* cost = buf1 + NVOL;
    float* inv1 = cost + NCOST;
    float* inv2 = inv1 + NPIX;
    float* rden = inv2 + NPIX;
    float* Abuf = rden + NPIX;
    float* Sbuf = Abuf + NPIX;
    float* partials = buf1;  // dead before lga#1 writes buf1

    const dim3 lgrid(WW / TW, HH / TH, NDCH);

    // 0. zero the atomic accumulators
    hipMemsetAsync(rden, 0, NPIX * sizeof(float), stream);
    hipMemsetAsync(Abuf, 0, NPIX * sizeof(float), stream);
    hipMemsetAsync(Sbuf, 0, NPIX * sizeof(float), stream);

    // 1. conv3d (channel-split x4) + combine
    conv3d_split_kernel<<<dim3(W0 / 64, H0 / 4, (D0 / CZC) * 4), 256, 0, stream>>>(x, cw, partials);
    combine_kernel<<<(NCOST4 + 255) / 256, 256, 0, stream>>>((const float4*)partials, (float4*)cost);
    // 2. guidance inverse L1 norms
    invnorm_kernel<<<(NPIX4 + 255) / 256, 256, 0, stream>>>((const float4*)lg1, (float4*)inv1);
    invnorm_kernel<<<(NPIX4 + 255) / 256, 256, 0, stream>>>((const float4*)lg2, (float4*)inv2);
    // 3. trilinear upsample
    resize_kernel<<<(int)((NVOL + 255) / 256), 256, 0, stream>>>(cost, buf0);
    // 4. LGA passes (d-split). #2 fuses softmax exp+denominator; #4 fuses final reduce.
    lga_tiled_kernel<0><<<lgrid, NTHR, 0, stream>>>(buf0, buf1, lg1, inv1, nullptr, nullptr, nullptr);
    lga_tiled_kernel<1><<<lgrid, NTHR, 0, stream>>>(buf1, buf0, lg1, inv1, nullptr, nullptr, rden);
    rcp_kernel<<<(NPIX4 + 255) / 256, 256, 0, stream>>>((float4*)rden);
    lga_tiled_kernel<0><<<lgrid, NTHR, 0, stream>>>(buf0, buf1, lg2, inv2, rden, nullptr, nullptr);
    lga_tiled_kernel<2><<<lgrid, NTHR, 0, stream>>>(buf1, nullptr, lg2, inv2, nullptr, Abuf, Sbuf);
    // 5. finish: normalize + expectation
    finish_kernel<<<(NPIX4 + 255) / 256, 256, 0, stream>>>((const float4*)Abuf, (const float4*)Sbuf, (float4*)out);
}

// Round 7
// 954.021 us; speedup vs baseline: 10.6897x; 1.1447x over previous
//
#include <hip/hip_runtime.h>
#include <hip/hip_bf16.h>
#include <math.h>

#define C_IN   32
#define D0     64
#define H0     96
#define W0     192
#define DD     193
#define HH     288
#define WW     576
#define NPIX   (HH*WW)            // 165888
#define NPIX4  (NPIX/4)           // 41472
#define NVOL   ((size_t)DD*NPIX)  // 32,016,384
#define NCOST  (D0*H0*W0)         // 1,179,648
#define NCOST4 (NCOST/4)          // 294912

// ---------------- LDS-tiled conv3d, channel-split x4
#define CZC   8
#define CSL   (CZC + 2)        // 10 slices (z-halo)
#define CROWS 6
#define CSTR  72               // padded row stride (words)

__global__ __launch_bounds__(256)
void conv3d_split_kernel(const float* __restrict__ x,
                         const float* __restrict__ w,
                         float* __restrict__ partial) {
    __shared__ __align__(16) float sb[2][CSL][CROWS][CSTR];
    const int tid = threadIdx.x;
    const int tx = tid & 63, ty = tid >> 6;
    const int wb = blockIdx.x * 64, hb = blockIdx.y * 4;
    const int zc = blockIdx.z & 7, part = blockIdx.z >> 3;
    const int z0 = zc * CZC;
    const int cbase = part * 8;

    float acc[CZC];
    #pragma unroll
    for (int i = 0; i < CZC; ++i) acc[i] = 0.f;

    const float4 f4zero = {0.f, 0.f, 0.f, 0.f};

    #define STAGE(b, ci)                                                          \
    {                                                                             \
        const float* xc = x + (size_t)(ci) * (D0 * H0 * W0);                      \
        _Pragma("unroll")                                                         \
        for (int t0 = 0; t0 < 4; ++t0) {                                          \
            int t = t0 * 256 + tid;                                               \
            if (t < 960) {                                                        \
                int sl = t / 96; int rem = t - sl * 96;                           \
                int r = rem >> 4, v = rem & 15;                                   \
                int zz = z0 - 1 + sl, hh = hb - 1 + r;                            \
                bool ok = (unsigned)zz < (unsigned)D0 && (unsigned)hh < (unsigned)H0; \
                float4 val = ok ? *(const float4*)(xc + ((size_t)zz * H0 + hh) * W0 + wb + 4 * v) \
                                : f4zero;                                         \
                *(float4*)&sb[b][sl][r][4 + 4 * v] = val;                         \
            }                                                                     \
        }                                                                         \
        if (tid < 120) {                                                          \
            int sl = tid / 12; int e = tid - sl * 12;                             \
            int r = e >> 1, side = e & 1;                                         \
            int zz = z0 - 1 + sl, hh = hb - 1 + r;                                \
            int ww = side ? wb + 64 : wb - 1;                                     \
            bool ok = (unsigned)zz < (unsigned)D0 && (unsigned)hh < (unsigned)H0  \
                      && (unsigned)ww < (unsigned)W0;                             \
            sb[b][sl][r][side ? 68 : 3] = ok ? xc[((size_t)zz * H0 + hh) * W0 + ww] : 0.f; \
        }                                                                         \
    }

    STAGE(0, cbase);
    __syncthreads();

    for (int c = 0; c < 8; ++c) {
        const int b = c & 1;
        if (c + 1 < 8) STAGE(b ^ 1, cbase + c + 1);

        const float* wc = w + (cbase + c) * 27;
        float wr[27];
        #pragma unroll
        for (int t = 0; t < 27; ++t) wr[t] = wc[t];

        #pragma unroll
        for (int sl = 0; sl < CSL; ++sl) {
            float tap[9];
            #pragma unroll
            for (int i = 0; i < 3; ++i)
                #pragma unroll
                for (int j = 0; j < 3; ++j)
                    tap[i * 3 + j] = sb[b][sl][ty + i][tx + 3 + j];
            if (sl < CZC) {
                float cs = 0.f;
                #pragma unroll
                for (int t = 0; t < 9; ++t) cs += wr[t] * tap[t];
                acc[sl] += cs;
            }
            if (sl >= 1 && sl - 1 < CZC) {
                float cs = 0.f;
                #pragma unroll
                for (int t = 0; t < 9; ++t) cs += wr[9 + t] * tap[t];
                acc[sl - 1] += cs;
            }
            if (sl >= 2) {
                float cs = 0.f;
                #pragma unroll
                for (int t = 0; t < 9; ++t) cs += wr[18 + t] * tap[t];
                acc[sl - 2] += cs;
            }
        }
        __syncthreads();
    }
    #undef STAGE

    float* po = partial + (size_t)part * NCOST;
    #pragma unroll
    for (int i = 0; i < CZC; ++i)
        po[((size_t)(z0 + i) * H0 + (hb + ty)) * W0 + (wb + tx)] = acc[i];
}

// ---------------- combine 4 partials -> cost (float4)
__global__ void combine_kernel(const float4* __restrict__ partial, float4* __restrict__ cost) {
    int i = blockIdx.x * 256 + threadIdx.x;
    if (i >= NCOST4) return;
    float4 a = partial[i];
    float4 b = partial[i + NCOST4];
    float4 c = partial[i + 2 * NCOST4];
    float4 d = partial[i + 3 * NCOST4];
    float4 r;
    r.x = a.x + b.x + c.x + d.x;
    r.y = a.y + b.y + c.y + d.y;
    r.z = a.z + b.z + c.z + d.z;
    r.w = a.w + b.w + c.w + d.w;
    cost[i] = r;
}

// ---------------- per-pixel 1/L1-norm over 75 guidance channels (float4)
__global__ void invnorm_kernel(const float4* __restrict__ lg, float4* __restrict__ inv) {
    int p = blockIdx.x * 256 + threadIdx.x;
    if (p >= NPIX4) return;
    float4 s = {0.f, 0.f, 0.f, 0.f};
    for (int c = 0; c < 75; ++c) {
        float4 v = lg[(size_t)c * NPIX4 + p];
        s.x += fabsf(v.x); s.y += fabsf(v.y); s.z += fabsf(v.z); s.w += fabsf(v.w);
    }
    float4 r;
    r.x = 1.0f / fmaxf(s.x, 1e-12f);
    r.y = 1.0f / fmaxf(s.y, 1e-12f);
    r.z = 1.0f / fmaxf(s.z, 1e-12f);
    r.w = 1.0f / fmaxf(s.w, 1e-12f);
    inv[p] = r;
}

// ---------------- trilinear resize cost(64,96,192) -> out(193,288,576)
__global__ void resize_kernel(const float* __restrict__ cost, float* __restrict__ out) {
    size_t idx = (size_t)blockIdx.x * 256 + threadIdx.x;
    if (idx >= NVOL) return;
    int w = (int)(idx % WW);
    int t = (int)(idx / WW);
    int h = t % HH;
    int d = t / HH;

    float sd = fminf(fmaxf((d + 0.5f) * (64.0f / 193.0f) - 0.5f, 0.0f), 63.0f);
    int d0 = (int)floorf(sd); int d1 = min(d0 + 1, 63); float fd = sd - (float)d0;
    float sh = fminf(fmaxf((h + 0.5f) * (96.0f / 288.0f) - 0.5f, 0.0f), 95.0f);
    int h0 = (int)floorf(sh); int h1 = min(h0 + 1, 95); float fh = sh - (float)h0;
    float sw = fminf(fmaxf((w + 0.5f) * (192.0f / 576.0f) - 0.5f, 0.0f), 191.0f);
    int w0 = (int)floorf(sw); int w1 = min(w0 + 1, 191); float fw = sw - (float)w0;

    #define CV(dz, hy, wx) cost[((size_t)(dz) * H0 + (hy)) * W0 + (wx)]
    float v000 = CV(d0, h0, w0), v001 = CV(d0, h0, w1);
    float v010 = CV(d0, h1, w0), v011 = CV(d0, h1, w1);
    float v100 = CV(d1, h0, w0), v101 = CV(d1, h0, w1);
    float v110 = CV(d1, h1, w0), v111 = CV(d1, h1, w1);
    #undef CV
    float a = v000 * (1.f - fw) + v001 * fw;
    float b = v010 * (1.f - fw) + v011 * fw;
    float c = v100 * (1.f - fw) + v101 * fw;
    float e = v110 * (1.f - fw) + v111 * fw;
    float lo = a * (1.f - fh) + b * fh;
    float hi = c * (1.f - fh) + e * fh;
    out[idx] = lo * (1.f - fd) + hi * fd;
}

// ---------------- LDS-tiled LGA pass, d-split x3
// MODE 0: plain store. MODE 1: store exp(-v), atomic per-pixel sum into accS.
// MODE 2: no store; accumulate A=sum v*d, S=sum |v|, atomics into accA/accS.
#define TW 64
#define TH 8
#define HWT 68
#define HHT 12
#define NCELL (HWT*HHT)   // 816
#define NTHR 512
#define DCHUNK 65
#define NDCH  3           // ceil(193/65)

template<int MODE>
__global__ __launch_bounds__(NTHR, 2)   // allow ~256 VGPR: keep 75 g-weights in arch VGPRs, no AGPR spill
void lga_tiled_kernel(const float* __restrict__ in, float* __restrict__ out,
                      const float* __restrict__ g, const float* __restrict__ inv,
                      const float* __restrict__ inscale,
                      float* __restrict__ accAbuf, float* __restrict__ accSbuf) {
    __shared__ float sbuf[2][NCELL];
    const int tid = threadIdx.x;
    const int tx = tid & 63, ty = tid >> 6;
    const int wb = blockIdx.x * TW, hb = blockIdx.y * TH;
    const int pix = (hb + ty) * WW + (wb + tx);
    const int ds = blockIdx.z * DCHUNK;
    const int de = min(ds + DCHUNK, DD);
    const int e0 = max(ds - 1, 0);
    const int emax = min(de, DD - 1);

    const int c0 = tid, c1 = tid + NTHR;
    const bool has1 = (c1 < NCELL);
    int r0 = c0 / HWT, q0 = c0 - r0 * HWT;
    int hh0 = hb - 2 + r0, ww0 = wb - 2 + q0;
    const bool v0 = (unsigned)hh0 < (unsigned)HH && (unsigned)ww0 < (unsigned)WW;
    const size_t off0 = v0 ? (size_t)hh0 * WW + ww0 : 0;
    const float is0 = (inscale != nullptr && v0) ? inscale[off0] : 1.0f;
    int r1 = c1 / HWT, q1 = c1 - r1 * HWT;
    int hh1 = hb - 2 + r1, ww1 = wb - 2 + q1;
    const bool v1 = has1 && (unsigned)hh1 < (unsigned)HH && (unsigned)ww1 < (unsigned)WW;
    const size_t off1 = v1 ? (size_t)hh1 * WW + ww1 : 0;
    const float is1 = (inscale != nullptr && v1) ? inscale[off1] : 1.0f;

    const float s = inv[pix];
    float g0[25], g1[25], g2[25];
    #pragma unroll
    for (int c = 0; c < 25; ++c) g0[c] = g[(size_t)c * NPIX + pix] * s;
    #pragma unroll
    for (int c = 0; c < 25; ++c) g1[c] = g[(size_t)(25 + c) * NPIX + pix] * s;
    #pragma unroll
    for (int c = 0; c < 25; ++c) g2[c] = g[(size_t)(50 + c) * NPIX + pix] * s;

    {
        const float* sl = in + (size_t)e0 * NPIX;
        sbuf[e0 & 1][c0] = v0 ? sl[off0] * is0 : 0.0f;
        if (has1) sbuf[e0 & 1][c1] = v1 ? sl[off1] * is1 : 0.0f;
    }

    float accA = 0.f, accB = 0.f;
    float aloc = 0.f, sloc = 0.f;

    #define EMIT(n, val)                                                          \
    {                                                                             \
        if constexpr (MODE == 0) {                                                \
            out[(size_t)(n) * NPIX + pix] = (val);                                \
        } else if constexpr (MODE == 1) {                                         \
            float ev = __expf(-(val));                                            \
            out[(size_t)(n) * NPIX + pix] = ev;                                   \
            sloc += ev;                                                           \
        } else {                                                                  \
            aloc += (val) * (float)(n);                                           \
            sloc += fabsf(val);                                                   \
        }                                                                         \
    }

    for (int e = e0; e <= emax; ++e) {
        __syncthreads();
        if (e < emax) {
            const float* nsl = in + (size_t)(e + 1) * NPIX;
            float a = v0 ? nsl[off0] * is0 : 0.0f;
            float b = v1 ? nsl[off1] * is1 : 0.0f;
            float* nb = sbuf[(e + 1) & 1];
            nb[c0] = a;
            if (has1) nb[c1] = b;
        }
        const float* cur = sbuf[e & 1];
        float cc0 = 0.f, cc1 = 0.f, cc2 = 0.f;
        #pragma unroll
        for (int i = 0; i < 5; ++i) {
            const float* row = cur + (ty + i) * HWT + tx;
            #pragma unroll
            for (int j = 0; j < 5; ++j) {
                float v = row[j];
                cc0 += g0[i * 5 + j] * v;
                cc1 += g1[i * 5 + j] * v;
                cc2 += g2[i * 5 + j] * v;
            }
        }
        int n = e - 1;
        if (n >= ds && n < de) {
            float rr = accA + cc2;
            EMIT(n, rr);
        }
        accA = accB + cc1;
        accB = cc0;
    }
    if (de == DD) {
        EMIT(DD - 1, accA);  // slice DD is zero-pad: no c2 term
    }
    #undef EMIT

    if constexpr (MODE == 1) {
        atomicAdd(&accSbuf[pix], sloc);
    } else if constexpr (MODE == 2) {
        atomicAdd(&accAbuf[pix], aloc);
        atomicAdd(&accSbuf[pix], sloc);
    }
}

// ---------------- reciprocal in place (float4)
__global__ void rcp_kernel(float4* __restrict__ v) {
    int p = blockIdx.x * 256 + threadIdx.x;
    if (p >= NPIX4) return;
    float4 a = v[p];
    a.x = 1.0f / a.x; a.y = 1.0f / a.y; a.z = 1.0f / a.z; a.w = 1.0f / a.w;
    v[p] = a;
}

// ---------------- finish: out = A / max(S, eps) (float4)
__global__ void finish_kernel(const float4* __restrict__ A, const float4* __restrict__ S,
                              float4* __restrict__ out) {
    int p = blockIdx.x * 256 + threadIdx.x;
    if (p >= NPIX4) return;
    float4 a = A[p], s = S[p];
    float4 r;
    r.x = a.x / fmaxf(s.x, 1e-12f);
    r.y = a.y / fmaxf(s.y, 1e-12f);
    r.z = a.z / fmaxf(s.z, 1e-12f);
    r.w = a.w / fmaxf(s.w, 1e-12f);
    out[p] = r;
}

extern "C" void kernel_launch(void* const* d_in, const int* in_sizes, int n_in,
                              void* d_out, int out_size, void* d_ws, size_t ws_size,
                              hipStream_t stream) {
    const float* x    = (const float*)d_in[0];
    const float* lg1  = (const float*)d_in[1];
    const float* lg2  = (const float*)d_in[2];
    const float* cw   = (const float*)d_in[3];
    float* out = (float*)d_out;

    float* ws   = (float*)d_ws;
    float* buf0 = ws;
    float* buf1 = buf0 + NVOL;
    float* cost = buf1 + NVOL;
    float* inv1 = cost + NCOST;
    float* inv2 = inv1 + NPIX;
    float* rden = inv2 + NPIX;
    float* Abuf = rden + NPIX;
    float* Sbuf = Abuf + NPIX;
    float* partials = buf1;  // dead before lga#1 writes buf1

    const dim3 lgrid(WW / TW, HH / TH, NDCH);

    // 0. zero the atomic accumulators
    hipMemsetAsync(rden, 0, NPIX * sizeof(float), stream);
    hipMemsetAsync(Abuf, 0, NPIX * sizeof(float), stream);
    hipMemsetAsync(Sbuf, 0, NPIX * sizeof(float), stream);

    // 1. conv3d (channel-split x4) + combine
    conv3d_split_kernel<<<dim3(W0 / 64, H0 / 4, (D0 / CZC) * 4), 256, 0, stream>>>(x, cw, partials);
    combine_kernel<<<(NCOST4 + 255) / 256, 256, 0, stream>>>((const float4*)partials, (float4*)cost);
    // 2. guidance inverse L1 norms
    invnorm_kernel<<<(NPIX4 + 255) / 256, 256, 0, stream>>>((const float4*)lg1, (float4*)inv1);
    invnorm_kernel<<<(NPIX4 + 255) / 256, 256, 0, stream>>>((const float4*)lg2, (float4*)inv2);
    // 3. trilinear upsample
    resize_kernel<<<(int)((NVOL + 255) / 256), 256, 0, stream>>>(cost, buf0);
    // 4. LGA passes (d-split x3). #2 fuses softmax exp+denominator; #4 fuses final reduce.
    lga_tiled_kernel<0><<<lgrid, NTHR, 0, stream>>>(buf0, buf1, lg1, inv1, nullptr, nullptr, nullptr);
    lga_tiled_kernel<1><<<lgrid, NTHR, 0, stream>>>(buf1, buf0, lg1, inv1, nullptr, nullptr, rden);
    rcp_kernel<<<(NPIX4 + 255) / 256, 256, 0, stream>>>((float4*)rden);
    lga_tiled_kernel<0><<<lgrid, NTHR, 0, stream>>>(buf0, buf1, lg2, inv2, rden, nullptr, nullptr);
    lga_tiled_kernel<2><<<lgrid, NTHR, 0, stream>>>(buf1, nullptr, lg2, inv2, nullptr, Abuf, Sbuf);
    // 5. finish: normalize + expectation
    finish_kernel<<<(NPIX4 + 255) / 256, 256, 0, stream>>>((const float4*)Abuf, (const float4*)Sbuf, (float4*)out);
}

// Round 8
// 953.599 us; speedup vs baseline: 10.6945x; 1.0004x over previous
//
#include <hip/hip_runtime.h>
#include <hip/hip_bf16.h>
#include <math.h>

#define C_IN   32
#define D0     64
#define H0     96
#define W0     192
#define DD     193
#define HH     288
#define WW     576
#define NPIX   (HH*WW)            // 165888
#define NPIX4  (NPIX/4)           // 41472
#define NVOL   ((size_t)DD*NPIX)  // 32,016,384
#define NCOST  (D0*H0*W0)         // 1,179,648
#define NCOST4 (NCOST/4)          // 294912

// ---------------- LDS-tiled conv3d, channel-split x4
#define CZC   8
#define CSL   (CZC + 2)        // 10 slices (z-halo)
#define CROWS 6
#define CSTR  72               // padded row stride (words)

__global__ __launch_bounds__(256)
void conv3d_split_kernel(const float* __restrict__ x,
                         const float* __restrict__ w,
                         float* __restrict__ partial) {
    __shared__ __align__(16) float sb[2][CSL][CROWS][CSTR];
    const int tid = threadIdx.x;
    const int tx = tid & 63, ty = tid >> 6;
    const int wb = blockIdx.x * 64, hb = blockIdx.y * 4;
    const int zc = blockIdx.z & 7, part = blockIdx.z >> 3;
    const int z0 = zc * CZC;
    const int cbase = part * 8;

    float acc[CZC];
    #pragma unroll
    for (int i = 0; i < CZC; ++i) acc[i] = 0.f;

    const float4 f4zero = {0.f, 0.f, 0.f, 0.f};

    #define STAGE(b, ci)                                                          \
    {                                                                             \
        const float* xc = x + (size_t)(ci) * (D0 * H0 * W0);                      \
        _Pragma("unroll")                                                         \
        for (int t0 = 0; t0 < 4; ++t0) {                                          \
            int t = t0 * 256 + tid;                                               \
            if (t < 960) {                                                        \
                int sl = t / 96; int rem = t - sl * 96;                           \
                int r = rem >> 4, v = rem & 15;                                   \
                int zz = z0 - 1 + sl, hh = hb - 1 + r;                            \
                bool ok = (unsigned)zz < (unsigned)D0 && (unsigned)hh < (unsigned)H0; \
                float4 val = ok ? *(const float4*)(xc + ((size_t)zz * H0 + hh) * W0 + wb + 4 * v) \
                                : f4zero;                                         \
                *(float4*)&sb[b][sl][r][4 + 4 * v] = val;                         \
            }                                                                     \
        }                                                                         \
        if (tid < 120) {                                                          \
            int sl = tid / 12; int e = tid - sl * 12;                             \
            int r = e >> 1, side = e & 1;                                         \
            int zz = z0 - 1 + sl, hh = hb - 1 + r;                                \
            int ww = side ? wb + 64 : wb - 1;                                     \
            bool ok = (unsigned)zz < (unsigned)D0 && (unsigned)hh < (unsigned)H0  \
                      && (unsigned)ww < (unsigned)W0;                             \
            sb[b][sl][r][side ? 68 : 3] = ok ? xc[((size_t)zz * H0 + hh) * W0 + ww] : 0.f; \
        }                                                                         \
    }

    STAGE(0, cbase);
    __syncthreads();

    for (int c = 0; c < 8; ++c) {
        const int b = c & 1;
        if (c + 1 < 8) STAGE(b ^ 1, cbase + c + 1);

        const float* wc = w + (cbase + c) * 27;
        float wr[27];
        #pragma unroll
        for (int t = 0; t < 27; ++t) wr[t] = wc[t];

        #pragma unroll
        for (int sl = 0; sl < CSL; ++sl) {
            float tap[9];
            #pragma unroll
            for (int i = 0; i < 3; ++i)
                #pragma unroll
                for (int j = 0; j < 3; ++j)
                    tap[i * 3 + j] = sb[b][sl][ty + i][tx + 3 + j];
            if (sl < CZC) {
                float cs = 0.f;
                #pragma unroll
                for (int t = 0; t < 9; ++t) cs += wr[t] * tap[t];
                acc[sl] += cs;
            }
            if (sl >= 1 && sl - 1 < CZC) {
                float cs = 0.f;
                #pragma unroll
                for (int t = 0; t < 9; ++t) cs += wr[9 + t] * tap[t];
                acc[sl - 1] += cs;
            }
            if (sl >= 2) {
                float cs = 0.f;
                #pragma unroll
                for (int t = 0; t < 9; ++t) cs += wr[18 + t] * tap[t];
                acc[sl - 2] += cs;
            }
        }
        __syncthreads();
    }
    #undef STAGE

    float* po = partial + (size_t)part * NCOST;
    #pragma unroll
    for (int i = 0; i < CZC; ++i)
        po[((size_t)(z0 + i) * H0 + (hb + ty)) * W0 + (wb + tx)] = acc[i];
}

// ---------------- combine 4 partials -> cost (float4)
__global__ void combine_kernel(const float4* __restrict__ partial, float4* __restrict__ cost) {
    int i = blockIdx.x * 256 + threadIdx.x;
    if (i >= NCOST4) return;
    float4 a = partial[i];
    float4 b = partial[i + NCOST4];
    float4 c = partial[i + 2 * NCOST4];
    float4 d = partial[i + 3 * NCOST4];
    float4 r;
    r.x = a.x + b.x + c.x + d.x;
    r.y = a.y + b.y + c.y + d.y;
    r.z = a.z + b.z + c.z + d.z;
    r.w = a.w + b.w + c.w + d.w;
    cost[i] = r;
}

// ---------------- per-pixel 1/L1-norm over 75 guidance channels (float4)
__global__ void invnorm_kernel(const float4* __restrict__ lg, float4* __restrict__ inv) {
    int p = blockIdx.x * 256 + threadIdx.x;
    if (p >= NPIX4) return;
    float4 s = {0.f, 0.f, 0.f, 0.f};
    for (int c = 0; c < 75; ++c) {
        float4 v = lg[(size_t)c * NPIX4 + p];
        s.x += fabsf(v.x); s.y += fabsf(v.y); s.z += fabsf(v.z); s.w += fabsf(v.w);
    }
    float4 r;
    r.x = 1.0f / fmaxf(s.x, 1e-12f);
    r.y = 1.0f / fmaxf(s.y, 1e-12f);
    r.z = 1.0f / fmaxf(s.z, 1e-12f);
    r.w = 1.0f / fmaxf(s.w, 1e-12f);
    inv[p] = r;
}

// ---------------- trilinear resize cost(64,96,192) -> out(193,288,576)
__global__ void resize_kernel(const float* __restrict__ cost, float* __restrict__ out) {
    size_t idx = (size_t)blockIdx.x * 256 + threadIdx.x;
    if (idx >= NVOL) return;
    int w = (int)(idx % WW);
    int t = (int)(idx / WW);
    int h = t % HH;
    int d = t / HH;

    float sd = fminf(fmaxf((d + 0.5f) * (64.0f / 193.0f) - 0.5f, 0.0f), 63.0f);
    int d0 = (int)floorf(sd); int d1 = min(d0 + 1, 63); float fd = sd - (float)d0;
    float sh = fminf(fmaxf((h + 0.5f) * (96.0f / 288.0f) - 0.5f, 0.0f), 95.0f);
    int h0 = (int)floorf(sh); int h1 = min(h0 + 1, 95); float fh = sh - (float)h0;
    float sw = fminf(fmaxf((w + 0.5f) * (192.0f / 576.0f) - 0.5f, 0.0f), 191.0f);
    int w0 = (int)floorf(sw); int w1 = min(w0 + 1, 191); float fw = sw - (float)w0;

    #define CV(dz, hy, wx) cost[((size_t)(dz) * H0 + (hy)) * W0 + (wx)]
    float v000 = CV(d0, h0, w0), v001 = CV(d0, h0, w1);
    float v010 = CV(d0, h1, w0), v011 = CV(d0, h1, w1);
    float v100 = CV(d1, h0, w0), v101 = CV(d1, h0, w1);
    float v110 = CV(d1, h1, w0), v111 = CV(d1, h1, w1);
    #undef CV
    float a = v000 * (1.f - fw) + v001 * fw;
    float b = v010 * (1.f - fw) + v011 * fw;
    float c = v100 * (1.f - fw) + v101 * fw;
    float e = v110 * (1.f - fw) + v111 * fw;
    float lo = a * (1.f - fh) + b * fh;
    float hi = c * (1.f - fh) + e * fh;
    out[idx] = lo * (1.f - fd) + hi * fd;
}

// ---------------- LDS-tiled LGA pass, d-split x3, async-STAGE split (T14)
// Loop order per slice: ds_write(e) [data loaded during prev compute] ->
// issue load(e+1) -> barrier -> compute(e). Double-buffered LDS; the single
// barrier per slice globally orders compute(e-2) before write(e) (same parity),
// so no write-after-read hazard.
// MODE 0: plain store. MODE 1: store exp(-v), atomic per-pixel sum into accS.
// MODE 2: no store; accumulate A=sum v*d, S=sum |v|, atomics into accA/accS.
#define TW 64
#define TH 8
#define HWT 68
#define HHT 12
#define NCELL (HWT*HHT)   // 816
#define NTHR 512
#define DCHUNK 65
#define NDCH  3           // ceil(193/65)

template<int MODE>
__global__ __launch_bounds__(NTHR, 2)
void lga_tiled_kernel(const float* __restrict__ in, float* __restrict__ out,
                      const float* __restrict__ g, const float* __restrict__ inv,
                      const float* __restrict__ inscale,
                      float* __restrict__ accAbuf, float* __restrict__ accSbuf) {
    __shared__ float sbuf[2][NCELL];
    const int tid = threadIdx.x;
    const int tx = tid & 63, ty = tid >> 6;
    const int wb = blockIdx.x * TW, hb = blockIdx.y * TH;
    const int pix = (hb + ty) * WW + (wb + tx);
    const int ds = blockIdx.z * DCHUNK;
    const int de = min(ds + DCHUNK, DD);
    const int e0 = max(ds - 1, 0);
    const int emax = min(de, DD - 1);

    const int c0 = tid, c1 = tid + NTHR;
    const bool has1 = (c1 < NCELL);
    int r0 = c0 / HWT, q0 = c0 - r0 * HWT;
    int hh0 = hb - 2 + r0, ww0 = wb - 2 + q0;
    const bool v0 = (unsigned)hh0 < (unsigned)HH && (unsigned)ww0 < (unsigned)WW;
    const size_t off0 = v0 ? (size_t)hh0 * WW + ww0 : 0;
    const float is0 = (inscale != nullptr && v0) ? inscale[off0] : 1.0f;
    int r1 = c1 / HWT, q1 = c1 - r1 * HWT;
    int hh1 = hb - 2 + r1, ww1 = wb - 2 + q1;
    const bool v1 = has1 && (unsigned)hh1 < (unsigned)HH && (unsigned)ww1 < (unsigned)WW;
    const size_t off1 = v1 ? (size_t)hh1 * WW + ww1 : 0;
    const float is1 = (inscale != nullptr && v1) ? inscale[off1] : 1.0f;

    const float s = inv[pix];
    float g0[25], g1[25], g2[25];
    #pragma unroll
    for (int c = 0; c < 25; ++c) g0[c] = g[(size_t)c * NPIX + pix] * s;
    #pragma unroll
    for (int c = 0; c < 25; ++c) g1[c] = g[(size_t)(25 + c) * NPIX + pix] * s;
    #pragma unroll
    for (int c = 0; c < 25; ++c) g2[c] = g[(size_t)(50 + c) * NPIX + pix] * s;

    // prologue: load slice e0 into registers
    float sa, sb2;
    {
        const float* sl = in + (size_t)e0 * NPIX;
        sa  = v0 ? sl[off0] * is0 : 0.0f;
        sb2 = v1 ? sl[off1] * is1 : 0.0f;
    }

    float accA = 0.f, accB = 0.f;
    float aloc = 0.f, sloc = 0.f;

    #define EMIT(n, val)                                                          \
    {                                                                             \
        if constexpr (MODE == 0) {                                                \
            out[(size_t)(n) * NPIX + pix] = (val);                                \
        } else if constexpr (MODE == 1) {                                         \
            float ev = __expf(-(val));                                            \
            out[(size_t)(n) * NPIX + pix] = ev;                                   \
            sloc += ev;                                                           \
        } else {                                                                  \
            aloc += (val) * (float)(n);                                           \
            sloc += fabsf(val);                                                   \
        }                                                                         \
    }

    for (int e = e0; e <= emax; ++e) {
        // 1. commit slice e to LDS (vmcnt waits here; data was in flight during prev compute)
        float* wp = sbuf[e & 1];
        wp[c0] = sa;
        if (has1) wp[c1] = sb2;
        // 2. issue loads for slice e+1 (latency hides under compute below)
        if (e < emax) {
            const float* nsl = in + (size_t)(e + 1) * NPIX;
            sa  = v0 ? nsl[off0] * is0 : 0.0f;
            sb2 = v1 ? nsl[off1] * is1 : 0.0f;
        }
        // 3. make slice e visible
        __syncthreads();
        // 4. compute slice e
        const float* cur = sbuf[e & 1];
        float cc0 = 0.f, cc1 = 0.f, cc2 = 0.f;
        #pragma unroll
        for (int i = 0; i < 5; ++i) {
            const float* row = cur + (ty + i) * HWT + tx;
            #pragma unroll
            for (int j = 0; j < 5; ++j) {
                float v = row[j];
                cc0 += g0[i * 5 + j] * v;
                cc1 += g1[i * 5 + j] * v;
                cc2 += g2[i * 5 + j] * v;
            }
        }
        int n = e - 1;
        if (n >= ds && n < de) {
            float rr = accA + cc2;
            EMIT(n, rr);
        }
        accA = accB + cc1;
        accB = cc0;
    }
    if (de == DD) {
        EMIT(DD - 1, accA);  // slice DD is zero-pad: no c2 term
    }
    #undef EMIT

    if constexpr (MODE == 1) {
        atomicAdd(&accSbuf[pix], sloc);
    } else if constexpr (MODE == 2) {
        atomicAdd(&accAbuf[pix], aloc);
        atomicAdd(&accSbuf[pix], sloc);
    }
}

// ---------------- reciprocal in place (float4)
__global__ void rcp_kernel(float4* __restrict__ v) {
    int p = blockIdx.x * 256 + threadIdx.x;
    if (p >= NPIX4) return;
    float4 a = v[p];
    a.x = 1.0f / a.x; a.y = 1.0f / a.y; a.z = 1.0f / a.z; a.w = 1.0f / a.w;
    v[p] = a;
}

// ---------------- finish: out = A / max(S, eps) (float4)
__global__ void finish_kernel(const float4* __restrict__ A, const float4* __restrict__ S,
                              float4* __restrict__ out) {
    int p = blockIdx.x * 256 + threadIdx.x;
    if (p >= NPIX4) return;
    float4 a = A[p], s = S[p];
    float4 r;
    r.x = a.x / fmaxf(s.x, 1e-12f);
    r.y = a.y / fmaxf(s.y, 1e-12f);
    r.z = a.z / fmaxf(s.z, 1e-12f);
    r.w = a.w / fmaxf(s.w, 1e-12f);
    out[p] = r;
}

extern "C" void kernel_launch(void* const* d_in, const int* in_sizes, int n_in,
                              void* d_out, int out_size, void* d_ws, size_t ws_size,
                              hipStream_t stream) {
    const float* x    = (const float*)d_in[0];
    const float* lg1  = (const float*)d_in[1];
    const float* lg2  = (const float*)d_in[2];
    const float* cw   = (const float*)d_in[3];
    float* out = (float*)d_out;

    float* ws   = (float*)d_ws;
    float* buf0 = ws;
    float* buf1 = buf0 + NVOL;
    float* cost = buf1 + NVOL;
    float* inv1 = cost + NCOST;
    float* inv2 = inv1 + NPIX;
    float* rden = inv2 + NPIX;
    float* Abuf = rden + NPIX;
    float* Sbuf = Abuf + NPIX;
    float* partials = buf1;  // dead before lga#1 writes buf1

    const dim3 lgrid(WW / TW, HH / TH, NDCH);

    // 0. zero the atomic accumulators
    hipMemsetAsync(rden, 0, NPIX * sizeof(float), stream);
    hipMemsetAsync(Abuf, 0, NPIX * sizeof(float), stream);
    hipMemsetAsync(Sbuf, 0, NPIX * sizeof(float), stream);

    // 1. conv3d (channel-split x4) + combine
    conv3d_split_kernel<<<dim3(W0 / 64, H0 / 4, (D0 / CZC) * 4), 256, 0, stream>>>(x, cw, partials);
    combine_kernel<<<(NCOST4 + 255) / 256, 256, 0, stream>>>((const float4*)partials, (float4*)cost);
    // 2. guidance inverse L1 norms
    invnorm_kernel<<<(NPIX4 + 255) / 256, 256, 0, stream>>>((const float4*)lg1, (float4*)inv1);
    invnorm_kernel<<<(NPIX4 + 255) / 256, 256, 0, stream>>>((const float4*)lg2, (float4*)inv2);
    // 3. trilinear upsample
    resize_kernel<<<(int)((NVOL + 255) / 256), 256, 0, stream>>>(cost, buf0);
    // 4. LGA passes (d-split x3). #2 fuses softmax exp+denominator; #4 fuses final reduce.
    lga_tiled_kernel<0><<<lgrid, NTHR, 0, stream>>>(buf0, buf1, lg1, inv1, nullptr, nullptr, nullptr);
    lga_tiled_kernel<1><<<lgrid, NTHR, 0, stream>>>(buf1, buf0, lg1, inv1, nullptr, nullptr, rden);
    rcp_kernel<<<(NPIX4 + 255) / 256, 256, 0, stream>>>((float4*)rden);
    lga_tiled_kernel<0><<<lgrid, NTHR, 0, stream>>>(buf0, buf1, lg2, inv2, rden, nullptr, nullptr);
    lga_tiled_kernel<2><<<lgrid, NTHR, 0, stream>>>(buf1, nullptr, lg2, inv2, nullptr, Abuf, Sbuf);
    // 5. finish: normalize + expectation
    finish_kernel<<<(NPIX4 + 255) / 256, 256, 0, stream>>>((const float4*)Abuf, (const float4*)Sbuf, (float4*)out);
}